// Round 10
// baseline (868.519 us; speedup 1.0000x reference)
//
#include <hip/hip_runtime.h>
#include <hip/hip_bf16.h>

typedef unsigned short u16;
typedef _Float16 f16x8 __attribute__((ext_vector_type(8)));
typedef float f32x4 __attribute__((ext_vector_type(4)));
typedef unsigned short u16x8 __attribute__((ext_vector_type(8)));
typedef unsigned int u32x4 __attribute__((ext_vector_type(4)));

constexpr int kB = 2;
constexpr int kS = 1024;
constexpr int kD = 512;
constexpr int kH = 8;
constexpr int kDK = 64;
constexpr int kL = 4;
constexpr int kV = 32000;
constexpr int kM = kB * kS;   // 2048
constexpr int kNB = kV / 128; // 250

__device__ __forceinline__ u16 f2fh(float x) {           // fp16 RTN
  _Float16 h = (_Float16)x;
  return __builtin_bit_cast(u16, h);
}
__device__ __forceinline__ float fh2f(u16 h) {
  return (float)__builtin_bit_cast(_Float16, h);
}
__device__ __forceinline__ u16 f2bh(float x) {           // bf16 RTN (exp store)
  unsigned u = __builtin_bit_cast(unsigned, x);
  unsigned r = u + 0x7fffu + ((u >> 16) & 1u);
  return (u16)(r >> 16);
}
__device__ __forceinline__ float bh2f(u16 h) {
  return __builtin_bit_cast(float, (unsigned)h << 16);
}
__device__ __forceinline__ void gload16(const u16* g, u16* l) {
  __builtin_amdgcn_global_load_lds(
      (const __attribute__((address_space(1))) unsigned int*)g,
      (__attribute__((address_space(3))) unsigned int*)l, 16, 0, 0);
}
// swizzled u16 index for element (row, k) in a [*][512] fp16 array
__device__ __forceinline__ size_t swz_idx(int row, int k) {
  return (size_t)row * kD + (k & ~63) + ((((k >> 3) & 7) ^ (row & 7)) << 3) + (k & 7);
}

// ------------------------------------------- weight conversion (transpose)
__global__ __launch_bounds__(256)
void conv_qkv(const float* __restrict__ Wq, const float* __restrict__ Wk,
              const float* __restrict__ Wv, u16* __restrict__ oh) {
  __shared__ float ld[64][65];
  const int kc = blockIdx.x, h = blockIdx.y, z = blockIdx.z;
  const int mat = z >> 3, lj = z & 7;
  const float* src = (mat == 0 ? Wq : mat == 1 ? Wk : Wv) +
                     ((size_t)(lj * kH + h)) * kD * kDK + (size_t)kc * 64 * kDK;
  const int t = threadIdx.x;
#pragma unroll
  for (int i = 0; i < 16; ++i) {
    const int idx = i * 256 + t;
    ld[idx >> 6][idx & 63] = src[idx];
  }
  __syncthreads();
  const int dkr = t >> 2, jb = t & 3;
  const size_t rowbase = ((size_t)lj * 1536 + mat * kD + h * kDK + dkr) * kD + kc * 64;
#pragma unroll
  for (int q = 0; q < 2; ++q) {
    const int jj = jb + q * 4;
    const int jsw = jj ^ (dkr & 7);
    u16x8 hi;
#pragma unroll
    for (int e = 0; e < 8; ++e) hi[e] = f2fh(ld[jj * 8 + e][dkr]);
    *(u16x8*)&oh[rowbase + jsw * 8] = hi;
  }
}

__global__ __launch_bounds__(256)
void conv_sq(const float* __restrict__ Wo, const float* __restrict__ w1,
             const float* __restrict__ w2, u16* __restrict__ woh,
             u16* __restrict__ w1h, u16* __restrict__ w2h) {
  __shared__ float ld[64][65];
  const int kc = blockIdx.x, nc = blockIdx.y, mid = blockIdx.z;
  const float* src;
  u16* dh;
  if (mid < 8) { src = Wo + (size_t)mid * kD * kD; dh = woh + (size_t)mid * kD * kD; }
  else if (mid < 12) { int l = mid - 8; src = w1 + (size_t)l * kD * kD; dh = w1h + (size_t)l * kD * kD; }
  else { int l = mid - 12; src = w2 + (size_t)l * kD * kD; dh = w2h + (size_t)l * kD * kD; }
  const int t = threadIdx.x;
#pragma unroll
  for (int i = 0; i < 16; ++i) {
    const int idx = i * 256 + t;
    const int kl = idx >> 6, nl = idx & 63;
    ld[kl][nl] = src[(size_t)(kc * 64 + kl) * kD + nc * 64 + nl];
  }
  __syncthreads();
  const int nr = t >> 2, jb = t & 3;
  const size_t rowbase = (size_t)(nc * 64 + nr) * kD + kc * 64;
#pragma unroll
  for (int q = 0; q < 2; ++q) {
    const int jj = jb + q * 4;
    const int jsw = jj ^ (nr & 7);
    u16x8 hi;
#pragma unroll
    for (int e = 0; e < 8; ++e) hi[e] = f2fh(ld[jj * 8 + e][nr]);
    *(u16x8*)&dh[rowbase + jsw * 8] = hi;
  }
}

__global__ __launch_bounds__(256)
void conv_emb(const float* __restrict__ emb, u16* __restrict__ oh) {
  const int chunk = blockIdx.x * 256 + threadIdx.x;
  const int n = chunk >> 6, j = chunk & 63;
  const float* s = &emb[(size_t)n * kD + j * 8];
  float4 a = *(const float4*)s, b = *(const float4*)(s + 4);
  u16x8 hi;
  hi[0] = f2fh(a.x); hi[1] = f2fh(a.y); hi[2] = f2fh(a.z); hi[3] = f2fh(a.w);
  hi[4] = f2fh(b.x); hi[5] = f2fh(b.y); hi[6] = f2fh(b.z); hi[7] = f2fh(b.w);
  *(u16x8*)&oh[(size_t)n * kD + (j & ~7) * 8 + (((j & 7) ^ (n & 7)) << 3)] = hi;
}

// LN gain/bias fp32 -> interleaved fp16 pairs (g,b) packed in one u32 per elem
__global__ __launch_bounds__(256)
void conv_gb(const float* __restrict__ g, const float* __restrict__ b,
             unsigned* __restrict__ out) {
  const size_t e0 = ((size_t)blockIdx.x * 256 + threadIdx.x) * 8;
  float4 ga = *(const float4*)&g[e0], gc = *(const float4*)&g[e0 + 4];
  float4 ba = *(const float4*)&b[e0], bc = *(const float4*)&b[e0 + 4];
  u32x4 o0, o1;
  o0[0] = (unsigned)f2fh(ga.x) | ((unsigned)f2fh(ba.x) << 16);
  o0[1] = (unsigned)f2fh(ga.y) | ((unsigned)f2fh(ba.y) << 16);
  o0[2] = (unsigned)f2fh(ga.z) | ((unsigned)f2fh(ba.z) << 16);
  o0[3] = (unsigned)f2fh(ga.w) | ((unsigned)f2fh(ba.w) << 16);
  o1[0] = (unsigned)f2fh(gc.x) | ((unsigned)f2fh(bc.x) << 16);
  o1[1] = (unsigned)f2fh(gc.y) | ((unsigned)f2fh(bc.y) << 16);
  o1[2] = (unsigned)f2fh(gc.z) | ((unsigned)f2fh(bc.z) << 16);
  o1[3] = (unsigned)f2fh(gc.w) | ((unsigned)f2fh(bc.w) << 16);
  *(u32x4*)&out[e0] = o0;
  *(u32x4*)&out[e0 + 4] = o1;
}

// ---------------------------------------------------------------- embed + PE
__global__ __launch_bounds__(256)
void embed_kernel(const int* __restrict__ tokens, const float* __restrict__ emb,
                  float* __restrict__ x, u16* __restrict__ xh) {
  const int row = blockIdx.x;
  const int s = row & (kS - 1);
  const int tok = tokens[row];
  const float scl = sqrtf((float)kD);
  for (int d = threadIdx.x; d < kD; d += 256) {
    float e = emb[(size_t)tok * kD + d];
    float den = powf(10000.0f, 2.0f * (float)d / (float)kD);
    float ang = (float)s / den;
    float pe = ((d & 1) == 0) ? sinf(ang) : cosf(ang);
    float o = (e + pe) * scl;
    x[(size_t)row * kD + d] = o;
    xh[swz_idx(row, d)] = f2fh(o);
  }
}

// --------------------------------------------------- MFMA GEMM, fp16 inputs
// C = A @ B^T. A: [M][K] fp16 pre-swizzled. B: [N][K] fp16 pre-swizzled.
// 2-phase double-buffered K-loop with global_load_lds(16B) staging.
// OUT: 0 fp32 [M][Nd]; 1 fp16 swizzled [M][512];
//      2 qkv: Q,K row-major [b,h,s,dk]; V transposed [b,h,dk,s] (LDS transpose);
//      3 bf16 exp(c) [M][Nd] + deterministic per-row partial sums.
// XSW: XCD-aware block swizzle over a 1-D grid (vocab).
template <int BM, int BN, int OUT, int BIAS, int RELU, int XSW = 0>
__global__ __launch_bounds__(256)
void mgemm2(const u16* __restrict__ Ah, const u16* __restrict__ Bh,
            float* __restrict__ Cf, u16* __restrict__ Ch,
            const float* __restrict__ bias, float* __restrict__ partials,
            int Kd, int Nd) {
  static_assert(BM == BN, "");
  constexpr int MF = BM / 32, NF = BN / 32;
  constexpr int TA = BM * 64;                       // u16 per tile
  constexpr int BUF = 2 * TA;                       // A + B
  __shared__ __align__(16) u16 lds[2 * BUF];
  __shared__ float plds[OUT == 3 ? 2 * BM : 1];
  const int t = threadIdx.x;
  const int lane = t & 63, g = lane >> 4, li = lane & 15;
  const int w = t >> 6, wr = w >> 1, wc = w & 1;
  int m0, n0, nidx;
  if (XSW) {
    const int phys = blockIdx.x;
    const int cpx = gridDim.x >> 3;
    const int lin = (phys & 7) * cpx + (phys >> 3);
    m0 = (lin & (kM / BM - 1)) * BM;
    nidx = lin / (kM / BM);
    n0 = nidx * BN;
  } else {
    m0 = blockIdx.x * BM;
    nidx = blockIdx.y;
    n0 = nidx * BN;
  }

  f32x4 acc[MF][NF];
#pragma unroll
  for (int i = 0; i < MF; ++i)
#pragma unroll
    for (int j = 0; j < NF; ++j) acc[i][j] = (f32x4){0.f, 0.f, 0.f, 0.f};

  auto stage = [&](int c, int k0) {
    u16* base = &lds[c * BUF];
#pragma unroll
    for (int it = 0; it < BM / 32; ++it) {
      const int idx = it * 256 + t;
      const int r = idx >> 3, j = (idx & 7) * 8;
      gload16(&Ah[(size_t)(m0 + r) * Kd + k0 + j], &base[idx * 8]);
      gload16(&Bh[(size_t)(n0 + r) * Kd + k0 + j], &base[TA + idx * 8]);
    }
  };
  auto compute = [&](int c) {
    const u16* base = &lds[c * BUF];
#pragma unroll
    for (int s = 0; s < 2; ++s) {
      const int s4g = s * 4 + g;
      f16x8 fah[MF], fbh[NF];
#pragma unroll
      for (int fm = 0; fm < MF; ++fm) {
        const int row = wr * (BM / 2) + fm * 16 + li;
        fah[fm] = *(const f16x8*)&base[row * 64 + ((s4g ^ (row & 7)) << 3)];
      }
#pragma unroll
      for (int fn = 0; fn < NF; ++fn) {
        const int row = wc * (BN / 2) + fn * 16 + li;
        fbh[fn] = *(const f16x8*)&base[TA + row * 64 + ((s4g ^ (row & 7)) << 3)];
      }
#pragma unroll
      for (int fm = 0; fm < MF; ++fm)
#pragma unroll
        for (int fn = 0; fn < NF; ++fn)
          acc[fm][fn] = __builtin_amdgcn_mfma_f32_16x16x32_f16(
              fah[fm], fbh[fn], acc[fm][fn], 0, 0, 0);
    }
  };

  stage(0, 0);
  __syncthreads();
  int cur = 0;
  for (int k0 = 64; k0 < Kd; k0 += 64) {
    stage(cur ^ 1, k0);
    compute(cur);
    __syncthreads();
    cur ^= 1;
  }
  compute(cur);

  const int vmat = (OUT == 2) ? (n0 >> 9) : 0;    // uniform per block
  // epilogue: D col = lane&15, row = (lane>>4)*4 + reg
#pragma unroll
  for (int fm = 0; fm < MF; ++fm)
#pragma unroll
    for (int fn = 0; fn < NF; ++fn)
#pragma unroll
      for (int r = 0; r < 4; ++r) {
        const int m = m0 + wr * (BM / 2) + fm * 16 + g * 4 + r;
        const int n = n0 + wc * (BN / 2) + fn * 16 + li;
        float c = acc[fm][fn][r];
        if (BIAS) c += bias[n];
        if (RELU) c = fmaxf(c, 0.0f);
        if (OUT == 0) {
          Cf[(size_t)m * Nd + n] = c;
        } else if (OUT == 1) {
          Ch[swz_idx(m, n)] = f2fh(c);
        } else if (OUT == 2) {
          if (vmat < 2) {                                  // Q,K: [b,h,s,dk]
            const int h = (n >> 6) & 7, dk = n & 63;
            const int b_ = m >> 10, s_ = m & (kS - 1);
            Ch[(size_t)vmat * kM * kD +
               (((size_t)(b_ * kH + h) * kS + s_) * kDK + dk)] = f2fh(c);
          }
          // V handled below via LDS transpose
        } else {
          u16 q = f2bh(__expf(c));
          Ch[(size_t)m * Nd + n] = q;
          acc[fm][fn][r] = bh2f(q);
        }
      }
  if (OUT == 2 && vmat == 2) {
    // transpose tile in LDS, write V^T [b,h,dk,s] coalesced
    u16* ldsT = lds;                                       // [BN][BM+2] u16
    constexpr int TS = BM + 2;
    __syncthreads();                                       // staging done
#pragma unroll
    for (int fm = 0; fm < MF; ++fm)
#pragma unroll
      for (int fn = 0; fn < NF; ++fn)
#pragma unroll
        for (int r = 0; r < 4; ++r) {
          const int ml = wr * (BM / 2) + fm * 16 + g * 4 + r;
          const int nl = wc * (BN / 2) + fn * 16 + li;
          ldsT[nl * TS + ml] = f2fh(acc[fm][fn][r]);
        }
    __syncthreads();
    const int b_ = m0 >> 10;
    const int s0_ = m0 & (kS - 1);                         // seq offset (FIX)
#pragma unroll
    for (int rep = 0; rep < BM * BN / 256 / 8; ++rep) {
      const int idx = rep * 256 + t;
      const int nl = idx >> (31 - __builtin_clz(BM / 8));  // idx / (BM/8)
      const int c8 = (idx & (BM / 8 - 1)) * 8;
      const int nn = n0 + nl;
      const int h = (nn >> 6) & 7, dk = nn & 63;
      u16x8 v = *(const u16x8*)&ldsT[nl * TS + c8];
      *(u16x8*)&Ch[2 * (size_t)kM * kD +
                   ((size_t)(b_ * kH + h) * kDK + dk) * kS + s0_ + c8] = v;
    }
  }
  if (OUT == 3) {
#pragma unroll
    for (int fm = 0; fm < MF; ++fm)
#pragma unroll
      for (int r = 0; r < 4; ++r) {
        float sv = 0.f;
#pragma unroll
        for (int fn = 0; fn < NF; ++fn) sv += acc[fm][fn][r];
        sv += __shfl_xor(sv, 1); sv += __shfl_xor(sv, 2);
        sv += __shfl_xor(sv, 4); sv += __shfl_xor(sv, 8);
        if (li == 0) plds[wc * BM + wr * (BM / 2) + fm * 16 + g * 4 + r] = sv;
      }
    __syncthreads();
    if (t < BM)
      partials[(size_t)(m0 + t) * (Nd / BN) + nidx] = plds[t] + plds[BM + t];
  }
}

// -------- MFMA flash attention: no LDS staging, no barriers, direct L2 reads
// q/k: [b,h,s,dk] fp16; vt: [b,h,dk,s] fp16. out fp16 swizzled [M][512].
__global__ __launch_bounds__(256)
void attn_kernel(const u16* __restrict__ qg, const u16* __restrict__ kg,
                 const u16* __restrict__ vtg, u16* __restrict__ aoh) {
  __shared__ __align__(16) u16 Pt[2][64][40];
  const int t = threadIdx.x;
  const int lane = t & 63;
  const int g = lane >> 4, li = lane & 15;
  const int w = t >> 6;
  const int bh = blockIdx.y;
  const int q0 = blockIdx.x * 64;
  const size_t base = (size_t)bh * kS * kDK;
  const size_t vbase = (size_t)bh * kDK * kS;
  const int qrow = q0 + w * 16 + li;
  const f16x8 qf0 = *(const f16x8*)&qg[base + (size_t)qrow * kDK + g * 8];
  const f16x8 qf1 = *(const f16x8*)&qg[base + (size_t)qrow * kDK + 32 + g * 8];

  float m_[4] = {-1e30f, -1e30f, -1e30f, -1e30f};
  float l_[4] = {0.f, 0.f, 0.f, 0.f};
  f32x4 apv[4];
#pragma unroll
  for (int i = 0; i < 4; ++i) apv[i] = (f32x4){0.f, 0.f, 0.f, 0.f};

#pragma unroll 2
  for (int kt = 0; kt < kS / 64; ++kt) {
    f32x4 s[4];
#pragma unroll
    for (int nf = 0; nf < 4; ++nf) {
      const size_t krow = base + (size_t)(kt * 64 + nf * 16 + li) * kDK;
      const f16x8 k0 = *(const f16x8*)&kg[krow + g * 8];
      const f16x8 k1 = *(const f16x8*)&kg[krow + 32 + g * 8];
      f32x4 sa = (f32x4){0.f, 0.f, 0.f, 0.f};
      sa = __builtin_amdgcn_mfma_f32_16x16x32_f16(qf0, k0, sa, 0, 0, 0);
      sa = __builtin_amdgcn_mfma_f32_16x16x32_f16(qf1, k1, sa, 0, 0, 0);
      s[nf] = sa;
    }
    float corr[4];
#pragma unroll
    for (int rr = 0; rr < 4; ++rr) {
      float tm = fmaxf(fmaxf(s[0][rr], s[1][rr]), fmaxf(s[2][rr], s[3][rr])) * 0.125f;
      tm = fmaxf(tm, __shfl_xor(tm, 1));
      tm = fmaxf(tm, __shfl_xor(tm, 2));
      tm = fmaxf(tm, __shfl_xor(tm, 4));
      tm = fmaxf(tm, __shfl_xor(tm, 8));
      const float nm = fmaxf(m_[rr], tm);
      corr[rr] = __expf(m_[rr] - nm);
      m_[rr] = nm;
    }
    float tsum[4] = {0.f, 0.f, 0.f, 0.f};
    u16 pb[4][4];
#pragma unroll
    for (int nf = 0; nf < 4; ++nf)
#pragma unroll
      for (int rr = 0; rr < 4; ++rr) {
        float p = __expf(s[nf][rr] * 0.125f - m_[rr]);
        tsum[rr] += p;
        pb[nf][rr] = f2fh(p);
      }
#pragma unroll
    for (int rr = 0; rr < 4; ++rr) {
      float ts = tsum[rr];
      ts += __shfl_xor(ts, 1); ts += __shfl_xor(ts, 2);
      ts += __shfl_xor(ts, 4); ts += __shfl_xor(ts, 8);
      l_[rr] = l_[rr] * corr[rr] + ts;
#pragma unroll
      for (int nf = 0; nf < 4; ++nf) apv[nf][rr] *= corr[rr];
    }
    // P round-trip through wave-local LDS rows (no barrier needed)
#pragma unroll
    for (int nf = 0; nf < 4; ++nf)
#pragma unroll
      for (int rr = 0; rr < 4; ++rr)
        Pt[nf >> 1][w * 16 + g * 4 + rr][(nf & 1) * 16 + li] = pb[nf][rr];
    const f16x8 p0 = *(const f16x8*)&Pt[0][w * 16 + li][g * 8];
    const f16x8 p1 = *(const f16x8*)&Pt[1][w * 16 + li][g * 8];
#pragma unroll
    for (int nf = 0; nf < 4; ++nf) {
      const size_t vrow = vbase + (size_t)(nf * 16 + li) * kS + kt * 64;
      const f16x8 v0 = *(const f16x8*)&vtg[vrow + g * 8];
      const f16x8 v1 = *(const f16x8*)&vtg[vrow + 32 + g * 8];
      apv[nf] = __builtin_amdgcn_mfma_f32_16x16x32_f16(p0, v0, apv[nf], 0, 0, 0);
      apv[nf] = __builtin_amdgcn_mfma_f32_16x16x32_f16(p1, v1, apv[nf], 0, 0, 0);
    }
  }
  const int b_ = bh >> 3, h_ = bh & 7;
#pragma unroll
  for (int rr = 0; rr < 4; ++rr) {
    const float inv = 1.0f / l_[rr];
    const int row = q0 + w * 16 + g * 4 + rr;
    const int m = b_ * kS + row;
#pragma unroll
    for (int nf = 0; nf < 4; ++nf) {
      const int d = h_ * kDK + nf * 16 + li;
      aoh[swz_idx(m, d)] = f2fh(apv[nf][rr] * inv);
    }
  }
}

// --------------------------------------------- residual + LayerNorm in place
__global__ __launch_bounds__(256)
void ln_kernel(float* __restrict__ x, const float* __restrict__ h,
               const unsigned* __restrict__ gb, u16* __restrict__ xh) {
  const int row = blockIdx.x;
  const int s = row & (kS - 1);
  const int t = threadIdx.x;
  float* xr = x + (size_t)row * kD;
  const float* hr = h + (size_t)row * kD;
  const float v0 = xr[t] + hr[t];
  const float v1 = xr[t + 256] + hr[t + 256];
  float sum = v0 + v1;
  float sq = v0 * v0 + v1 * v1;
#pragma unroll
  for (int off = 1; off < 64; off <<= 1) {
    sum += __shfl_xor(sum, off);
    sq += __shfl_xor(sq, off);
  }
  __shared__ float rs[4], rq[4];
  if ((t & 63) == 0) { rs[t >> 6] = sum; rq[t >> 6] = sq; }
  __syncthreads();
  sum = rs[0] + rs[1] + rs[2] + rs[3];
  sq = rq[0] + rq[1] + rq[2] + rq[3];
  const float mean = sum * (1.0f / kD);
  const float var = fmaxf(sq * (1.0f / kD) - mean * mean, 0.0f);
  const float inv = 1.0f / (sqrtf(var) + 1e-6f);
  const unsigned* gbr = gb + (size_t)s * kD;
  const unsigned p0 = gbr[t], p1 = gbr[t + 256];
  const float o0 = fh2f((u16)p0) * inv * (v0 - mean) + fh2f((u16)(p0 >> 16));
  const float o1 = fh2f((u16)p1) * inv * (v1 - mean) + fh2f((u16)(p1 >> 16));
  xr[t] = o0;
  xr[t + 256] = o1;
  xh[swz_idx(row, t)] = f2fh(o0);
  xh[swz_idx(row, t + 256)] = f2fh(o1);
}

// ---------------- fused rowsum + scale: p = bf16exp / sum, write fp32 d_out
__global__ __launch_bounds__(256)
void scale_kernel(const u16* __restrict__ expb, const float* __restrict__ partials,
                  float* __restrict__ out) {
  const int row = blockIdx.x;
  const int t = threadIdx.x;
  float s = (t < kNB) ? partials[(size_t)row * kNB + t] : 0.f;
#pragma unroll
  for (int off = 1; off < 64; off <<= 1) s += __shfl_xor(s, off);
  __shared__ float red[4];
  if ((t & 63) == 0) red[t >> 6] = s;
  __syncthreads();
  const float inv = 1.0f / (red[0] + red[1] + red[2] + red[3]);
  const u16x8* src = (const u16x8*)(expb + (size_t)row * kV);
  float4* dst = (float4*)(out + (size_t)row * kV);
  for (int i = t; i < kV / 8; i += 256) {
    u16x8 v = src[i];
    float4 a = make_float4(bh2f(v[0]) * inv, bh2f(v[1]) * inv,
                           bh2f(v[2]) * inv, bh2f(v[3]) * inv);
    float4 b = make_float4(bh2f(v[4]) * inv, bh2f(v[5]) * inv,
                           bh2f(v[6]) * inv, bh2f(v[7]) * inv);
    dst[i * 2] = a;
    dst[i * 2 + 1] = b;
  }
}

// ---------------------------------------------------------------------------
extern "C" void kernel_launch(void* const* d_in, const int* in_sizes, int n_in,
                              void* d_out, int out_size, void* d_ws, size_t ws_size,
                              hipStream_t stream) {
  (void)in_sizes; (void)n_in; (void)out_size; (void)ws_size;
  const int* tokens = (const int*)d_in[0];
  const float* emb = (const float*)d_in[1];
  const float* Wq = (const float*)d_in[2];
  const float* Wk = (const float*)d_in[3];
  const float* Wv = (const float*)d_in[4];
  const float* Wo = (const float*)d_in[5];
  const float* lng = (const float*)d_in[6];
  const float* lnb = (const float*)d_in[7];
  const float* w1 = (const float*)d_in[8];
  const float* b1 = (const float*)d_in[9];
  const float* w2 = (const float*)d_in[10];
  const float* b2 = (const float*)d_in[11];

  size_t off = 0;
  auto alloc = [&](size_t bytes) {
    void* p = (char*)d_ws + off;
    off += (bytes + 255) & ~(size_t)255;
    return p;
  };
  const size_t NA = (size_t)kM * kD;
  float* x = (float*)alloc(NA * 4);
  u16* xh = (u16*)alloc(NA * 2);
  u16* qkvb = (u16*)alloc(3 * NA * 2);
  u16* aoh = (u16*)alloc(NA * 2);
  float* t1 = (float*)alloc(NA * 4);
  u16* t1h = (u16*)alloc(NA * 2);
  float* ao2 = (float*)alloc(NA * 4);
  float* partials = (float*)alloc((size_t)kM * kNB * 4);
  u16* expb = (u16*)alloc((size_t)kM * kV * 2);     // 131 MB bf16 exp-logits
  u16* wqkvh = (u16*)alloc((size_t)8 * 1536 * kD * 2);
  u16* woh = (u16*)alloc((size_t)8 * kD * kD * 2);
  u16* w1h = (u16*)alloc((size_t)4 * kD * kD * 2);
  u16* w2h = (u16*)alloc((size_t)4 * kD * kD * 2);
  u16* embh = (u16*)alloc((size_t)kV * kD * 2);
  unsigned* gb = (unsigned*)alloc((size_t)kL * 3 * kS * kD * 4);

  conv_qkv<<<dim3(8, 8, 24), 256, 0, stream>>>(Wq, Wk, Wv, wqkvh);
  conv_sq<<<dim3(8, 8, 16), 256, 0, stream>>>(Wo, w1, w2, woh, w1h, w2h);
  conv_emb<<<kV * kD / 8 / 256, 256, 0, stream>>>(emb, embh);
  conv_gb<<<kL * 3 * kS * kD / 8 / 256, 256, 0, stream>>>(lng, lnb, gb);
  embed_kernel<<<kM, 256, 0, stream>>>(tokens, emb, x, xh);

  for (int l = 0; l < kL; ++l) {
    for (int j = 0; j < 2; ++j) {
      const size_t lj = (size_t)(l * 2 + j);
      mgemm2<128, 128, 2, 0, 0><<<dim3(kM / 128, 12), 256, 0, stream>>>(
          xh, wqkvh + lj * 1536 * kD, nullptr, qkvb, nullptr, nullptr, kD, 1536);
      attn_kernel<<<dim3(kS / 64, kB * kH), 256, 0, stream>>>(
          qkvb, qkvb + NA, qkvb + 2 * NA, aoh);
      mgemm2<64, 64, 0, 0, 0><<<dim3(kM / 64, kD / 64), 256, 0, stream>>>(
          aoh, woh + lj * kD * kD, t1, nullptr, nullptr, nullptr, kD, kD);
      ln_kernel<<<kM, 256, 0, stream>>>(x, t1, gb + (size_t)(l * 3 + j) * kS * kD, xh);
    }
    mgemm2<64, 64, 1, 1, 1><<<dim3(kM / 64, kD / 64), 256, 0, stream>>>(
        xh, w1h + (size_t)l * kD * kD, nullptr, t1h, b1 + (size_t)l * kD,
        nullptr, kD, kD);
    mgemm2<64, 64, 0, 1, 0><<<dim3(kM / 64, kD / 64), 256, 0, stream>>>(
        t1h, w2h + (size_t)l * kD * kD, ao2, nullptr, b2 + (size_t)l * kD,
        nullptr, kD, kD);
    ln_kernel<<<kM, 256, 0, stream>>>(x, ao2, gb + (size_t)(l * 3 + 2) * kS * kD, xh);
  }
  // vocab: bf16 exp(x @ emb^T) -> expb + partials (XCD-swizzled); rowsum+scale
  mgemm2<128, 128, 3, 0, 0, 1><<<dim3(kM / 128 * kNB), 256, 0, stream>>>(
      xh, embh, nullptr, expb, nullptr, partials, kD, kV);
  scale_kernel<<<kM, 256, 0, stream>>>(expb, partials, (float*)d_out);
}

// Round 11
// 690.594 us; speedup vs baseline: 1.2576x; 1.2576x over previous
//
#include <hip/hip_runtime.h>
#include <hip/hip_bf16.h>

typedef unsigned short u16;
typedef _Float16 f16x8 __attribute__((ext_vector_type(8)));
typedef float f32x4 __attribute__((ext_vector_type(4)));
typedef unsigned short u16x8 __attribute__((ext_vector_type(8)));
typedef unsigned int u32x4 __attribute__((ext_vector_type(4)));

constexpr int kB = 2;
constexpr int kS = 1024;
constexpr int kD = 512;
constexpr int kH = 8;
constexpr int kDK = 64;
constexpr int kL = 4;
constexpr int kV = 32000;
constexpr int kM = kB * kS;   // 2048
constexpr int kNB = kV / 128; // 250

__device__ __forceinline__ u16 f2fh(float x) {           // fp16 RTN
  _Float16 h = (_Float16)x;
  return __builtin_bit_cast(u16, h);
}
__device__ __forceinline__ float fh2f(u16 h) {
  return (float)__builtin_bit_cast(_Float16, h);
}
__device__ __forceinline__ u16 f2bh(float x) {           // bf16 RTN (exp store)
  unsigned u = __builtin_bit_cast(unsigned, x);
  unsigned r = u + 0x7fffu + ((u >> 16) & 1u);
  return (u16)(r >> 16);
}
__device__ __forceinline__ float bh2f(u16 h) {
  return __builtin_bit_cast(float, (unsigned)h << 16);
}
__device__ __forceinline__ void gload16(const u16* g, u16* l) {
  __builtin_amdgcn_global_load_lds(
      (const __attribute__((address_space(1))) unsigned int*)g,
      (__attribute__((address_space(3))) unsigned int*)l, 16, 0, 0);
}
// swizzled u16 index for element (row, k) in a [*][512] fp16 array
__device__ __forceinline__ size_t swz_idx(int row, int k) {
  return (size_t)row * kD + (k & ~63) + ((((k >> 3) & 7) ^ (row & 7)) << 3) + (k & 7);
}

// ------------------------------------------- weight conversion (transpose)
__global__ __launch_bounds__(256)
void conv_qkv(const float* __restrict__ Wq, const float* __restrict__ Wk,
              const float* __restrict__ Wv, u16* __restrict__ oh) {
  __shared__ float ld[64][65];
  const int kc = blockIdx.x, h = blockIdx.y, z = blockIdx.z;
  const int mat = z >> 3, lj = z & 7;
  const float* src = (mat == 0 ? Wq : mat == 1 ? Wk : Wv) +
                     ((size_t)(lj * kH + h)) * kD * kDK + (size_t)kc * 64 * kDK;
  const int t = threadIdx.x;
#pragma unroll
  for (int i = 0; i < 16; ++i) {
    const int idx = i * 256 + t;
    ld[idx >> 6][idx & 63] = src[idx];
  }
  __syncthreads();
  const int dkr = t >> 2, jb = t & 3;
  const size_t rowbase = ((size_t)lj * 1536 + mat * kD + h * kDK + dkr) * kD + kc * 64;
#pragma unroll
  for (int q = 0; q < 2; ++q) {
    const int jj = jb + q * 4;
    const int jsw = jj ^ (dkr & 7);
    u16x8 hi;
#pragma unroll
    for (int e = 0; e < 8; ++e) hi[e] = f2fh(ld[jj * 8 + e][dkr]);
    *(u16x8*)&oh[rowbase + jsw * 8] = hi;
  }
}

__global__ __launch_bounds__(256)
void conv_sq(const float* __restrict__ Wo, const float* __restrict__ w1,
             const float* __restrict__ w2, u16* __restrict__ woh,
             u16* __restrict__ w1h, u16* __restrict__ w2h) {
  __shared__ float ld[64][65];
  const int kc = blockIdx.x, nc = blockIdx.y, mid = blockIdx.z;
  const float* src;
  u16* dh;
  if (mid < 8) { src = Wo + (size_t)mid * kD * kD; dh = woh + (size_t)mid * kD * kD; }
  else if (mid < 12) { int l = mid - 8; src = w1 + (size_t)l * kD * kD; dh = w1h + (size_t)l * kD * kD; }
  else { int l = mid - 12; src = w2 + (size_t)l * kD * kD; dh = w2h + (size_t)l * kD * kD; }
  const int t = threadIdx.x;
#pragma unroll
  for (int i = 0; i < 16; ++i) {
    const int idx = i * 256 + t;
    const int kl = idx >> 6, nl = idx & 63;
    ld[kl][nl] = src[(size_t)(kc * 64 + kl) * kD + nc * 64 + nl];
  }
  __syncthreads();
  const int nr = t >> 2, jb = t & 3;
  const size_t rowbase = (size_t)(nc * 64 + nr) * kD + kc * 64;
#pragma unroll
  for (int q = 0; q < 2; ++q) {
    const int jj = jb + q * 4;
    const int jsw = jj ^ (nr & 7);
    u16x8 hi;
#pragma unroll
    for (int e = 0; e < 8; ++e) hi[e] = f2fh(ld[jj * 8 + e][nr]);
    *(u16x8*)&dh[rowbase + jsw * 8] = hi;
  }
}

__global__ __launch_bounds__(256)
void conv_emb(const float* __restrict__ emb, u16* __restrict__ oh) {
  const int chunk = blockIdx.x * 256 + threadIdx.x;
  const int n = chunk >> 6, j = chunk & 63;
  const float* s = &emb[(size_t)n * kD + j * 8];
  float4 a = *(const float4*)s, b = *(const float4*)(s + 4);
  u16x8 hi;
  hi[0] = f2fh(a.x); hi[1] = f2fh(a.y); hi[2] = f2fh(a.z); hi[3] = f2fh(a.w);
  hi[4] = f2fh(b.x); hi[5] = f2fh(b.y); hi[6] = f2fh(b.z); hi[7] = f2fh(b.w);
  *(u16x8*)&oh[(size_t)n * kD + (j & ~7) * 8 + (((j & 7) ^ (n & 7)) << 3)] = hi;
}

// LN gain/bias fp32 -> interleaved fp16 pairs (g,b) packed in one u32 per elem
__global__ __launch_bounds__(256)
void conv_gb(const float* __restrict__ g, const float* __restrict__ b,
             unsigned* __restrict__ out) {
  const size_t e0 = ((size_t)blockIdx.x * 256 + threadIdx.x) * 8;
  float4 ga = *(const float4*)&g[e0], gc = *(const float4*)&g[e0 + 4];
  float4 ba = *(const float4*)&b[e0], bc = *(const float4*)&b[e0 + 4];
  u32x4 o0, o1;
  o0[0] = (unsigned)f2fh(ga.x) | ((unsigned)f2fh(ba.x) << 16);
  o0[1] = (unsigned)f2fh(ga.y) | ((unsigned)f2fh(ba.y) << 16);
  o0[2] = (unsigned)f2fh(ga.z) | ((unsigned)f2fh(ba.z) << 16);
  o0[3] = (unsigned)f2fh(ga.w) | ((unsigned)f2fh(ba.w) << 16);
  o1[0] = (unsigned)f2fh(gc.x) | ((unsigned)f2fh(bc.x) << 16);
  o1[1] = (unsigned)f2fh(gc.y) | ((unsigned)f2fh(bc.y) << 16);
  o1[2] = (unsigned)f2fh(gc.z) | ((unsigned)f2fh(bc.z) << 16);
  o1[3] = (unsigned)f2fh(gc.w) | ((unsigned)f2fh(bc.w) << 16);
  *(u32x4*)&out[e0] = o0;
  *(u32x4*)&out[e0 + 4] = o1;
}

// ---------------------------------------------------------------- embed + PE
__global__ __launch_bounds__(256)
void embed_kernel(const int* __restrict__ tokens, const float* __restrict__ emb,
                  float* __restrict__ x, u16* __restrict__ xh) {
  const int row = blockIdx.x;
  const int s = row & (kS - 1);
  const int tok = tokens[row];
  const float scl = sqrtf((float)kD);
  for (int d = threadIdx.x; d < kD; d += 256) {
    float e = emb[(size_t)tok * kD + d];
    float den = powf(10000.0f, 2.0f * (float)d / (float)kD);
    float ang = (float)s / den;
    float pe = ((d & 1) == 0) ? sinf(ang) : cosf(ang);
    float o = (e + pe) * scl;
    x[(size_t)row * kD + d] = o;
    xh[swz_idx(row, d)] = f2fh(o);
  }
}

// --------------------------------------------------- MFMA GEMM, fp16 inputs
// C = A @ B^T. A: [M][K] fp16 pre-swizzled. B: [N][K] fp16 pre-swizzled.
// 2-phase double-buffered K-loop with global_load_lds(16B) staging.
// OUT: 0 fp32 [M][Nd]; 1 fp16 swizzled [M][512]; 2 qkv fp16 scatter [b,h,s,dk];
//      3 bf16 exp(c) [M][Nd] + deterministic per-row partial sums.
template <int BM, int BN, int OUT, int BIAS, int RELU>
__global__ __launch_bounds__(256)
void mgemm2(const u16* __restrict__ Ah, const u16* __restrict__ Bh,
            float* __restrict__ Cf, u16* __restrict__ Ch,
            const float* __restrict__ bias, float* __restrict__ partials,
            int Kd, int Nd) {
  static_assert(BM == BN, "");
  constexpr int MF = BM / 32, NF = BN / 32;
  constexpr int TA = BM * 64;                       // u16 per tile
  constexpr int BUF = 2 * TA;                       // A + B
  __shared__ __align__(16) u16 lds[2 * BUF];
  __shared__ float plds[OUT == 3 ? 2 * BM : 1];
  const int t = threadIdx.x;
  const int lane = t & 63, g = lane >> 4, li = lane & 15;
  const int w = t >> 6, wr = w >> 1, wc = w & 1;
  const int m0 = blockIdx.x * BM, n0 = blockIdx.y * BN;

  f32x4 acc[MF][NF];
#pragma unroll
  for (int i = 0; i < MF; ++i)
#pragma unroll
    for (int j = 0; j < NF; ++j) acc[i][j] = (f32x4){0.f, 0.f, 0.f, 0.f};

  auto stage = [&](int c, int k0) {
    u16* base = &lds[c * BUF];
#pragma unroll
    for (int it = 0; it < BM / 32; ++it) {
      const int idx = it * 256 + t;
      const int r = idx >> 3, j = (idx & 7) * 8;
      gload16(&Ah[(size_t)(m0 + r) * Kd + k0 + j], &base[idx * 8]);
      gload16(&Bh[(size_t)(n0 + r) * Kd + k0 + j], &base[TA + idx * 8]);
    }
  };
  auto compute = [&](int c) {
    const u16* base = &lds[c * BUF];
#pragma unroll
    for (int s = 0; s < 2; ++s) {
      const int s4g = s * 4 + g;
      f16x8 fah[MF], fbh[NF];
#pragma unroll
      for (int fm = 0; fm < MF; ++fm) {
        const int row = wr * (BM / 2) + fm * 16 + li;
        fah[fm] = *(const f16x8*)&base[row * 64 + ((s4g ^ (row & 7)) << 3)];
      }
#pragma unroll
      for (int fn = 0; fn < NF; ++fn) {
        const int row = wc * (BN / 2) + fn * 16 + li;
        fbh[fn] = *(const f16x8*)&base[TA + row * 64 + ((s4g ^ (row & 7)) << 3)];
      }
#pragma unroll
      for (int fm = 0; fm < MF; ++fm)
#pragma unroll
        for (int fn = 0; fn < NF; ++fn)
          acc[fm][fn] = __builtin_amdgcn_mfma_f32_16x16x32_f16(
              fah[fm], fbh[fn], acc[fm][fn], 0, 0, 0);
    }
  };

  stage(0, 0);
  __syncthreads();
  int cur = 0;
  for (int k0 = 64; k0 < Kd; k0 += 64) {
    stage(cur ^ 1, k0);
    compute(cur);
    __syncthreads();
    cur ^= 1;
  }
  compute(cur);

  // epilogue: D col = lane&15, row = (lane>>4)*4 + reg
#pragma unroll
  for (int fm = 0; fm < MF; ++fm)
#pragma unroll
    for (int fn = 0; fn < NF; ++fn)
#pragma unroll
      for (int r = 0; r < 4; ++r) {
        const int m = m0 + wr * (BM / 2) + fm * 16 + g * 4 + r;
        const int n = n0 + wc * (BN / 2) + fn * 16 + li;
        float c = acc[fm][fn][r];
        if (BIAS) c += bias[n];
        if (RELU) c = fmaxf(c, 0.0f);
        if (OUT == 0) {
          Cf[(size_t)m * Nd + n] = c;
        } else if (OUT == 1) {
          Ch[swz_idx(m, n)] = f2fh(c);
        } else if (OUT == 2) {
          const int mat = n >> 9, h = (n >> 6) & 7, dk = n & 63;
          const int b_ = m >> 10, s_ = m & (kS - 1);
          Ch[((size_t)mat * kM) * kD +
             (((size_t)(b_ * kH + h) * kS + s_) * kDK + dk)] = f2fh(c);
        } else {
          u16 q = f2bh(__expf(c));
          Ch[(size_t)m * Nd + n] = q;
          acc[fm][fn][r] = bh2f(q);
        }
      }
  if (OUT == 3) {
#pragma unroll
    for (int fm = 0; fm < MF; ++fm)
#pragma unroll
      for (int r = 0; r < 4; ++r) {
        float sv = 0.f;
#pragma unroll
        for (int fn = 0; fn < NF; ++fn) sv += acc[fm][fn][r];
        sv += __shfl_xor(sv, 1); sv += __shfl_xor(sv, 2);
        sv += __shfl_xor(sv, 4); sv += __shfl_xor(sv, 8);
        if (li == 0) plds[wc * BM + wr * (BM / 2) + fm * 16 + g * 4 + r] = sv;
      }
    __syncthreads();
    if (t < BM)
      partials[(size_t)(m0 + t) * gridDim.y + blockIdx.y] = plds[t] + plds[BM + t];
  }
}

// ---------------- MFMA flash attention (fp16, double-buffered K/V staging)
__global__ __launch_bounds__(256)
void attn_kernel(const u16* __restrict__ qg, const u16* __restrict__ kg,
                 const u16* __restrict__ vg, u16* __restrict__ aoh) {
  __shared__ __align__(16) u16 Kt[2][2][64][40];
  __shared__ __align__(16) u16 Vt[2][2][64][40];
  __shared__ __align__(16) u16 Pt[2][64][40];
  const int t = threadIdx.x;
  const int lane = t & 63;
  const int g = lane >> 4, li = lane & 15;
  const int w = t >> 6;
  const int bh = blockIdx.y;
  const int q0 = blockIdx.x * 64;
  const size_t base = (size_t)bh * kS * kDK;
  const int r = t >> 2, dq = (t & 3) * 16;

  // stage Q via Pt scratch, pull per-wave A-frags
  {
    const u16* src = &qg[base + (size_t)(q0 + r) * kDK + dq];
    u16x8 a = *(const u16x8*)src;
    u16x8 b = *(const u16x8*)(src + 8);
    *(u16x8*)&Pt[dq >> 5][r][dq & 31] = a;
    *(u16x8*)&Pt[dq >> 5][r][(dq & 31) + 8] = b;
  }
  __syncthreads();
  f16x8 qf0 = *(const f16x8*)&Pt[0][w * 16 + li][g * 8];
  f16x8 qf1 = *(const f16x8*)&Pt[1][w * 16 + li][g * 8];
  __syncthreads();   // Pt free for P tiles

  float m_[4] = {-1e30f, -1e30f, -1e30f, -1e30f};
  float l_[4] = {0.f, 0.f, 0.f, 0.f};
  f32x4 apv[4];
#pragma unroll
  for (int i = 0; i < 4; ++i) apv[i] = (f32x4){0.f, 0.f, 0.f, 0.f};

  u16x8 ka, kb, va, vb;
  auto load_tile = [&](int kt) {
    const u16* ks = &kg[base + (size_t)(kt * 64 + r) * kDK + dq];
    ka = *(const u16x8*)ks;
    kb = *(const u16x8*)(ks + 8);
    const u16* vs = &vg[base + (size_t)(kt * 64 + r) * kDK + dq];
    va = *(const u16x8*)vs;
    vb = *(const u16x8*)(vs + 8);
  };
  auto store_tile = [&](int c) {
    *(u16x8*)&Kt[c][dq >> 5][r][dq & 31] = ka;
    *(u16x8*)&Kt[c][dq >> 5][r][(dq & 31) + 8] = kb;
    const int vc = r >> 5, ko = (r & 31) >> 3, kp = r & 7;
#pragma unroll
    for (int i = 0; i < 8; ++i) {
      const int d = dq + i;
      Vt[c][vc][d][((ko ^ (d >> 4)) << 3) | kp] = va[i];
    }
#pragma unroll
    for (int i = 0; i < 8; ++i) {
      const int d = dq + 8 + i;
      Vt[c][vc][d][((ko ^ (d >> 4)) << 3) | kp] = vb[i];
    }
  };

  load_tile(0);
  store_tile(0);
  for (int kt = 0; kt < kS / 64; ++kt) {
    const int c = kt & 1;
    if (kt < kS / 64 - 1) load_tile(kt + 1);   // issue next-tile loads early
    __syncthreads();                            // buf c ready
    f32x4 s[4];
#pragma unroll
    for (int nf = 0; nf < 4; ++nf) {
      f16x8 k0 = *(const f16x8*)&Kt[c][0][nf * 16 + li][g * 8];
      f16x8 k1 = *(const f16x8*)&Kt[c][1][nf * 16 + li][g * 8];
      f32x4 sa = (f32x4){0.f, 0.f, 0.f, 0.f};
      sa = __builtin_amdgcn_mfma_f32_16x16x32_f16(qf0, k0, sa, 0, 0, 0);
      sa = __builtin_amdgcn_mfma_f32_16x16x32_f16(qf1, k1, sa, 0, 0, 0);
      s[nf] = sa;
    }
    float corr[4];
#pragma unroll
    for (int rr = 0; rr < 4; ++rr) {
      float tm = fmaxf(fmaxf(s[0][rr], s[1][rr]), fmaxf(s[2][rr], s[3][rr])) * 0.125f;
      tm = fmaxf(tm, __shfl_xor(tm, 1));
      tm = fmaxf(tm, __shfl_xor(tm, 2));
      tm = fmaxf(tm, __shfl_xor(tm, 4));
      tm = fmaxf(tm, __shfl_xor(tm, 8));
      const float nm = fmaxf(m_[rr], tm);
      corr[rr] = __expf(m_[rr] - nm);
      m_[rr] = nm;
    }
    float tsum[4] = {0.f, 0.f, 0.f, 0.f};
    u16 pb[4][4];
#pragma unroll
    for (int nf = 0; nf < 4; ++nf)
#pragma unroll
      for (int rr = 0; rr < 4; ++rr) {
        float p = __expf(s[nf][rr] * 0.125f - m_[rr]);
        tsum[rr] += p;
        pb[nf][rr] = f2fh(p);
      }
#pragma unroll
    for (int rr = 0; rr < 4; ++rr) {
      float ts = tsum[rr];
      ts += __shfl_xor(ts, 1); ts += __shfl_xor(ts, 2);
      ts += __shfl_xor(ts, 4); ts += __shfl_xor(ts, 8);
      l_[rr] = l_[rr] * corr[rr] + ts;
#pragma unroll
      for (int nf = 0; nf < 4; ++nf) apv[nf][rr] *= corr[rr];
    }
#pragma unroll
    for (int nf = 0; nf < 4; ++nf)
#pragma unroll
      for (int rr = 0; rr < 4; ++rr)
        Pt[nf >> 1][w * 16 + g * 4 + rr][(nf & 1) * 16 + li] = pb[nf][rr];
    f16x8 p0 = *(const f16x8*)&Pt[0][w * 16 + li][g * 8];
    f16x8 p1 = *(const f16x8*)&Pt[1][w * 16 + li][g * 8];
#pragma unroll
    for (int nf = 0; nf < 4; ++nf) {
      f16x8 v0 = *(const f16x8*)&Vt[c][0][nf * 16 + li][((g ^ nf) & 3) * 8];
      f16x8 v1 = *(const f16x8*)&Vt[c][1][nf * 16 + li][((g ^ nf) & 3) * 8];
      apv[nf] = __builtin_amdgcn_mfma_f32_16x16x32_f16(p0, v0, apv[nf], 0, 0, 0);
      apv[nf] = __builtin_amdgcn_mfma_f32_16x16x32_f16(p1, v1, apv[nf], 0, 0, 0);
    }
    if (kt < kS / 64 - 1) store_tile(c ^ 1);    // write next tile after compute
  }
  const int b_ = bh >> 3, h_ = bh & 7;
#pragma unroll
  for (int rr = 0; rr < 4; ++rr) {
    const float inv = 1.0f / l_[rr];
    const int row = q0 + w * 16 + g * 4 + rr;
    const int m = b_ * kS + row;
#pragma unroll
    for (int nf = 0; nf < 4; ++nf) {
      const int d = h_ * kDK + nf * 16 + li;
      aoh[swz_idx(m, d)] = f2fh(apv[nf][rr] * inv);
    }
  }
}

// --------------------------------------------- residual + LayerNorm in place
__global__ __launch_bounds__(256)
void ln_kernel(float* __restrict__ x, const float* __restrict__ h,
               const unsigned* __restrict__ gb, u16* __restrict__ xh) {
  const int row = blockIdx.x;
  const int s = row & (kS - 1);
  const int t = threadIdx.x;
  float* xr = x + (size_t)row * kD;
  const float* hr = h + (size_t)row * kD;
  const float v0 = xr[t] + hr[t];
  const float v1 = xr[t + 256] + hr[t + 256];
  float sum = v0 + v1;
  float sq = v0 * v0 + v1 * v1;
#pragma unroll
  for (int off = 1; off < 64; off <<= 1) {
    sum += __shfl_xor(sum, off);
    sq += __shfl_xor(sq, off);
  }
  __shared__ float rs[4], rq[4];
  if ((t & 63) == 0) { rs[t >> 6] = sum; rq[t >> 6] = sq; }
  __syncthreads();
  sum = rs[0] + rs[1] + rs[2] + rs[3];
  sq = rq[0] + rq[1] + rq[2] + rq[3];
  const float mean = sum * (1.0f / kD);
  const float var = fmaxf(sq * (1.0f / kD) - mean * mean, 0.0f);
  const float inv = 1.0f / (sqrtf(var) + 1e-6f);
  const unsigned* gbr = gb + (size_t)s * kD;
  const unsigned p0 = gbr[t], p1 = gbr[t + 256];
  const float o0 = fh2f((u16)p0) * inv * (v0 - mean) + fh2f((u16)(p0 >> 16));
  const float o1 = fh2f((u16)p1) * inv * (v1 - mean) + fh2f((u16)(p1 >> 16));
  xr[t] = o0;
  xr[t + 256] = o1;
  xh[swz_idx(row, t)] = f2fh(o0);
  xh[swz_idx(row, t + 256)] = f2fh(o1);
}

// ---------------- fused rowsum + scale: p = bf16exp / sum, write fp32 d_out
__global__ __launch_bounds__(256)
void scale_kernel(const u16* __restrict__ expb, const float* __restrict__ partials,
                  float* __restrict__ out) {
  const int row = blockIdx.x;
  const int t = threadIdx.x;
  float s = (t < kNB) ? partials[(size_t)row * kNB + t] : 0.f;
#pragma unroll
  for (int off = 1; off < 64; off <<= 1) s += __shfl_xor(s, off);
  __shared__ float red[4];
  if ((t & 63) == 0) red[t >> 6] = s;
  __syncthreads();
  const float inv = 1.0f / (red[0] + red[1] + red[2] + red[3]);
  const u16x8* src = (const u16x8*)(expb + (size_t)row * kV);
  float4* dst = (float4*)(out + (size_t)row * kV);
  for (int i = t; i < kV / 8; i += 256) {
    u16x8 v = src[i];
    float4 a = make_float4(bh2f(v[0]) * inv, bh2f(v[1]) * inv,
                           bh2f(v[2]) * inv, bh2f(v[3]) * inv);
    float4 b = make_float4(bh2f(v[4]) * inv, bh2f(v[5]) * inv,
                           bh2f(v[6]) * inv, bh2f(v[7]) * inv);
    dst[i * 2] = a;
    dst[i * 2 + 1] = b;
  }
}

// ---------------------------------------------------------------------------
extern "C" void kernel_launch(void* const* d_in, const int* in_sizes, int n_in,
                              void* d_out, int out_size, void* d_ws, size_t ws_size,
                              hipStream_t stream) {
  (void)in_sizes; (void)n_in; (void)out_size; (void)ws_size;
  const int* tokens = (const int*)d_in[0];
  const float* emb = (const float*)d_in[1];
  const float* Wq = (const float*)d_in[2];
  const float* Wk = (const float*)d_in[3];
  const float* Wv = (const float*)d_in[4];
  const float* Wo = (const float*)d_in[5];
  const float* lng = (const float*)d_in[6];
  const float* lnb = (const float*)d_in[7];
  const float* w1 = (const float*)d_in[8];
  const float* b1 = (const float*)d_in[9];
  const float* w2 = (const float*)d_in[10];
  const float* b2 = (const float*)d_in[11];

  size_t off = 0;
  auto alloc = [&](size_t bytes) {
    void* p = (char*)d_ws + off;
    off += (bytes + 255) & ~(size_t)255;
    return p;
  };
  const size_t NA = (size_t)kM * kD;
  float* x = (float*)alloc(NA * 4);
  u16* xh = (u16*)alloc(NA * 2);
  u16* qkvb = (u16*)alloc(3 * NA * 2);
  u16* aoh = (u16*)alloc(NA * 2);
  float* t1 = (float*)alloc(NA * 4);
  u16* t1h = (u16*)alloc(NA * 2);
  float* ao2 = (float*)alloc(NA * 4);
  float* partials = (float*)alloc((size_t)kM * kNB * 4);
  u16* expb = (u16*)alloc((size_t)kM * kV * 2);     // 131 MB bf16 exp-logits
  u16* wqkvh = (u16*)alloc((size_t)8 * 1536 * kD * 2);
  u16* woh = (u16*)alloc((size_t)8 * kD * kD * 2);
  u16* w1h = (u16*)alloc((size_t)4 * kD * kD * 2);
  u16* w2h = (u16*)alloc((size_t)4 * kD * kD * 2);
  u16* embh = (u16*)alloc((size_t)kV * kD * 2);
  unsigned* gb = (unsigned*)alloc((size_t)kL * 3 * kS * kD * 4);

  conv_qkv<<<dim3(8, 8, 24), 256, 0, stream>>>(Wq, Wk, Wv, wqkvh);
  conv_sq<<<dim3(8, 8, 16), 256, 0, stream>>>(Wo, w1, w2, woh, w1h, w2h);
  conv_emb<<<kV * kD / 8 / 256, 256, 0, stream>>>(emb, embh);
  conv_gb<<<kL * 3 * kS * kD / 8 / 256, 256, 0, stream>>>(lng, lnb, gb);
  embed_kernel<<<kM, 256, 0, stream>>>(tokens, emb, x, xh);

  for (int l = 0; l < kL; ++l) {
    for (int j = 0; j < 2; ++j) {
      const size_t lj = (size_t)(l * 2 + j);
      mgemm2<128, 128, 2, 0, 0><<<dim3(kM / 128, 12), 256, 0, stream>>>(
          xh, wqkvh + lj * 1536 * kD, nullptr, qkvb, nullptr, nullptr, kD, 1536);
      attn_kernel<<<dim3(kS / 64, kB * kH), 256, 0, stream>>>(
          qkvb, qkvb + NA, qkvb + 2 * NA, aoh);
      mgemm2<64, 64, 0, 0, 0><<<dim3(kM / 64, kD / 64), 256, 0, stream>>>(
          aoh, woh + lj * kD * kD, t1, nullptr, nullptr, nullptr, kD, kD);
      ln_kernel<<<kM, 256, 0, stream>>>(x, t1, gb + (size_t)(l * 3 + j) * kS * kD, xh);
    }
    mgemm2<64, 64, 1, 1, 1><<<dim3(kM / 64, kD / 64), 256, 0, stream>>>(
        xh, w1h + (size_t)l * kD * kD, nullptr, t1h, b1 + (size_t)l * kD,
        nullptr, kD, kD);
    mgemm2<64, 64, 0, 1, 0><<<dim3(kM / 64, kD / 64), 256, 0, stream>>>(
        t1h, w2h + (size_t)l * kD * kD, ao2, nullptr, b2 + (size_t)l * kD,
        nullptr, kD, kD);
    ln_kernel<<<kM, 256, 0, stream>>>(x, ao2, gb + (size_t)(l * 3 + 2) * kS * kD, xh);
  }
  // vocab: bf16 exp(x @ emb^T) -> expb + partials; then fused rowsum+scale
  mgemm2<128, 128, 3, 0, 0><<<dim3(kM / 128, kNB), 256, 0, stream>>>(
      xh, embh, nullptr, expb, nullptr, partials, kD, kV);
  scale_kernel<<<kM, 256, 0, stream>>>(expb, partials, (float*)d_out);
}

// Round 13
// 679.409 us; speedup vs baseline: 1.2783x; 1.0165x over previous
//
#include <hip/hip_runtime.h>
#include <hip/hip_bf16.h>

typedef unsigned short u16;
typedef _Float16 f16x8 __attribute__((ext_vector_type(8)));
typedef float f32x4 __attribute__((ext_vector_type(4)));
typedef unsigned short u16x8 __attribute__((ext_vector_type(8)));
typedef unsigned int u32x4 __attribute__((ext_vector_type(4)));

constexpr int kB = 2;
constexpr int kS = 1024;
constexpr int kD = 512;
constexpr int kH = 8;
constexpr int kDK = 64;
constexpr int kL = 4;
constexpr int kV = 32000;
constexpr int kM = kB * kS;   // 2048
constexpr int kNB = kV / 128; // 250

__device__ __forceinline__ u16 f2fh(float x) {           // fp16 RTN
  _Float16 h = (_Float16)x;
  return __builtin_bit_cast(u16, h);
}
__device__ __forceinline__ float fh2f(u16 h) {
  return (float)__builtin_bit_cast(_Float16, h);
}
__device__ __forceinline__ u16 f2bh(float x) {           // bf16 RTN (exp store)
  unsigned u = __builtin_bit_cast(unsigned, x);
  unsigned r = u + 0x7fffu + ((u >> 16) & 1u);
  return (u16)(r >> 16);
}
__device__ __forceinline__ float bh2f(u16 h) {
  return __builtin_bit_cast(float, (unsigned)h << 16);
}
__device__ __forceinline__ void gload16(const u16* g, u16* l) {
  __builtin_amdgcn_global_load_lds(
      (const __attribute__((address_space(1))) unsigned int*)g,
      (__attribute__((address_space(3))) unsigned int*)l, 16, 0, 0);
}
// swizzled u16 index for element (row, k) in a [*][512] fp16 array
__device__ __forceinline__ size_t swz_idx(int row, int k) {
  return (size_t)row * kD + (k & ~63) + ((((k >> 3) & 7) ^ (row & 7)) << 3) + (k & 7);
}

// ------------------------------------------- weight conversion (transpose)
__global__ __launch_bounds__(256)
void conv_qkv(const float* __restrict__ Wq, const float* __restrict__ Wk,
              const float* __restrict__ Wv, u16* __restrict__ oh) {
  __shared__ float ld[64][65];
  const int kc = blockIdx.x, h = blockIdx.y, z = blockIdx.z;
  const int mat = z >> 3, lj = z & 7;
  const float* src = (mat == 0 ? Wq : mat == 1 ? Wk : Wv) +
                     ((size_t)(lj * kH + h)) * kD * kDK + (size_t)kc * 64 * kDK;
  const int t = threadIdx.x;
#pragma unroll
  for (int i = 0; i < 16; ++i) {
    const int idx = i * 256 + t;
    ld[idx >> 6][idx & 63] = src[idx];
  }
  __syncthreads();
  const int dkr = t >> 2, jb = t & 3;
  const size_t rowbase = ((size_t)lj * 1536 + mat * kD + h * kDK + dkr) * kD + kc * 64;
#pragma unroll
  for (int q = 0; q < 2; ++q) {
    const int jj = jb + q * 4;
    const int jsw = jj ^ (dkr & 7);
    u16x8 hi;
#pragma unroll
    for (int e = 0; e < 8; ++e) hi[e] = f2fh(ld[jj * 8 + e][dkr]);
    *(u16x8*)&oh[rowbase + jsw * 8] = hi;
  }
}

__global__ __launch_bounds__(256)
void conv_sq(const float* __restrict__ Wo, const float* __restrict__ w1,
             const float* __restrict__ w2, u16* __restrict__ woh,
             u16* __restrict__ w1h, u16* __restrict__ w2h) {
  __shared__ float ld[64][65];
  const int kc = blockIdx.x, nc = blockIdx.y, mid = blockIdx.z;
  const float* src;
  u16* dh;
  if (mid < 8) { src = Wo + (size_t)mid * kD * kD; dh = woh + (size_t)mid * kD * kD; }
  else if (mid < 12) { int l = mid - 8; src = w1 + (size_t)l * kD * kD; dh = w1h + (size_t)l * kD * kD; }
  else { int l = mid - 12; src = w2 + (size_t)l * kD * kD; dh = w2h + (size_t)l * kD * kD; }
  const int t = threadIdx.x;
#pragma unroll
  for (int i = 0; i < 16; ++i) {
    const int idx = i * 256 + t;
    const int kl = idx >> 6, nl = idx & 63;
    ld[kl][nl] = src[(size_t)(kc * 64 + kl) * kD + nc * 64 + nl];
  }
  __syncthreads();
  const int nr = t >> 2, jb = t & 3;
  const size_t rowbase = (size_t)(nc * 64 + nr) * kD + kc * 64;
#pragma unroll
  for (int q = 0; q < 2; ++q) {
    const int jj = jb + q * 4;
    const int jsw = jj ^ (nr & 7);
    u16x8 hi;
#pragma unroll
    for (int e = 0; e < 8; ++e) hi[e] = f2fh(ld[jj * 8 + e][nr]);
    *(u16x8*)&dh[rowbase + jsw * 8] = hi;
  }
}

__global__ __launch_bounds__(256)
void conv_emb(const float* __restrict__ emb, u16* __restrict__ oh) {
  const int chunk = blockIdx.x * 256 + threadIdx.x;
  const int n = chunk >> 6, j = chunk & 63;
  const float* s = &emb[(size_t)n * kD + j * 8];
  float4 a = *(const float4*)s, b = *(const float4*)(s + 4);
  u16x8 hi;
  hi[0] = f2fh(a.x); hi[1] = f2fh(a.y); hi[2] = f2fh(a.z); hi[3] = f2fh(a.w);
  hi[4] = f2fh(b.x); hi[5] = f2fh(b.y); hi[6] = f2fh(b.z); hi[7] = f2fh(b.w);
  *(u16x8*)&oh[(size_t)n * kD + (j & ~7) * 8 + (((j & 7) ^ (n & 7)) << 3)] = hi;
}

// LN gain/bias fp32 -> interleaved fp16 pairs (g,b) packed in one u32 per elem
__global__ __launch_bounds__(256)
void conv_gb(const float* __restrict__ g, const float* __restrict__ b,
             unsigned* __restrict__ out) {
  const size_t e0 = ((size_t)blockIdx.x * 256 + threadIdx.x) * 8;
  float4 ga = *(const float4*)&g[e0], gc = *(const float4*)&g[e0 + 4];
  float4 ba = *(const float4*)&b[e0], bc = *(const float4*)&b[e0 + 4];
  u32x4 o0, o1;
  o0[0] = (unsigned)f2fh(ga.x) | ((unsigned)f2fh(ba.x) << 16);
  o0[1] = (unsigned)f2fh(ga.y) | ((unsigned)f2fh(ba.y) << 16);
  o0[2] = (unsigned)f2fh(ga.z) | ((unsigned)f2fh(ba.z) << 16);
  o0[3] = (unsigned)f2fh(ga.w) | ((unsigned)f2fh(ba.w) << 16);
  o1[0] = (unsigned)f2fh(gc.x) | ((unsigned)f2fh(bc.x) << 16);
  o1[1] = (unsigned)f2fh(gc.y) | ((unsigned)f2fh(bc.y) << 16);
  o1[2] = (unsigned)f2fh(gc.z) | ((unsigned)f2fh(bc.z) << 16);
  o1[3] = (unsigned)f2fh(gc.w) | ((unsigned)f2fh(bc.w) << 16);
  *(u32x4*)&out[e0] = o0;
  *(u32x4*)&out[e0 + 4] = o1;
}

// ---------------------------------------------------------------- embed + PE
__global__ __launch_bounds__(256)
void embed_kernel(const int* __restrict__ tokens, const float* __restrict__ emb,
                  float* __restrict__ x, u16* __restrict__ xh) {
  const int row = blockIdx.x;
  const int s = row & (kS - 1);
  const int tok = tokens[row];
  const float scl = sqrtf((float)kD);
  for (int d = threadIdx.x; d < kD; d += 256) {
    float e = emb[(size_t)tok * kD + d];
    float den = powf(10000.0f, 2.0f * (float)d / (float)kD);
    float ang = (float)s / den;
    float pe = ((d & 1) == 0) ? sinf(ang) : cosf(ang);
    float o = (e + pe) * scl;
    x[(size_t)row * kD + d] = o;
    xh[swz_idx(row, d)] = f2fh(o);
  }
}

// --------------------------------------------------- MFMA GEMM, fp16 inputs
// C = A @ B^T. A: [M][K] fp16 pre-swizzled. B: [N][K] fp16 pre-swizzled.
// 2-phase double-buffered K-loop with global_load_lds(16B) staging.
// OUT: 0 fp32 [M][Nd]; 1 fp16 swizzled [M][512]; 2 qkv fp16 scatter [b,h,s,dk];
//      3 bf16 exp(c) [M][Nd] + deterministic per-row partial sums.
template <int BM, int BN, int OUT, int BIAS, int RELU>
__global__ __launch_bounds__(256)
void mgemm2(const u16* __restrict__ Ah, const u16* __restrict__ Bh,
            float* __restrict__ Cf, u16* __restrict__ Ch,
            const float* __restrict__ bias, float* __restrict__ partials,
            int Kd, int Nd) {
  static_assert(BM == BN, "");
  constexpr int MF = BM / 32, NF = BN / 32;
  constexpr int TA = BM * 64;                       // u16 per tile
  constexpr int BUF = 2 * TA;                       // A + B
  __shared__ __align__(16) u16 lds[2 * BUF];
  __shared__ float plds[OUT == 3 ? 2 * BM : 1];
  const int t = threadIdx.x;
  const int lane = t & 63, g = lane >> 4, li = lane & 15;
  const int w = t >> 6, wr = w >> 1, wc = w & 1;
  const int m0 = blockIdx.x * BM, n0 = blockIdx.y * BN;

  f32x4 acc[MF][NF];
#pragma unroll
  for (int i = 0; i < MF; ++i)
#pragma unroll
    for (int j = 0; j < NF; ++j) acc[i][j] = (f32x4){0.f, 0.f, 0.f, 0.f};

  auto stage = [&](int c, int k0) {
    u16* base = &lds[c * BUF];
#pragma unroll
    for (int it = 0; it < BM / 32; ++it) {
      const int idx = it * 256 + t;
      const int r = idx >> 3, j = (idx & 7) * 8;
      gload16(&Ah[(size_t)(m0 + r) * Kd + k0 + j], &base[idx * 8]);
      gload16(&Bh[(size_t)(n0 + r) * Kd + k0 + j], &base[TA + idx * 8]);
    }
  };
  auto compute = [&](int c) {
    const u16* base = &lds[c * BUF];
#pragma unroll
    for (int s = 0; s < 2; ++s) {
      const int s4g = s * 4 + g;
      f16x8 fah[MF], fbh[NF];
#pragma unroll
      for (int fm = 0; fm < MF; ++fm) {
        const int row = wr * (BM / 2) + fm * 16 + li;
        fah[fm] = *(const f16x8*)&base[row * 64 + ((s4g ^ (row & 7)) << 3)];
      }
#pragma unroll
      for (int fn = 0; fn < NF; ++fn) {
        const int row = wc * (BN / 2) + fn * 16 + li;
        fbh[fn] = *(const f16x8*)&base[TA + row * 64 + ((s4g ^ (row & 7)) << 3)];
      }
#pragma unroll
      for (int fm = 0; fm < MF; ++fm)
#pragma unroll
        for (int fn = 0; fn < NF; ++fn)
          acc[fm][fn] = __builtin_amdgcn_mfma_f32_16x16x32_f16(
              fah[fm], fbh[fn], acc[fm][fn], 0, 0, 0);
    }
  };

  stage(0, 0);
  __syncthreads();
  int cur = 0;
  for (int k0 = 64; k0 < Kd; k0 += 64) {
    stage(cur ^ 1, k0);
    compute(cur);
    __syncthreads();
    cur ^= 1;
  }
  compute(cur);

  // epilogue: D col = lane&15, row = (lane>>4)*4 + reg
#pragma unroll
  for (int fm = 0; fm < MF; ++fm)
#pragma unroll
    for (int fn = 0; fn < NF; ++fn)
#pragma unroll
      for (int r = 0; r < 4; ++r) {
        const int m = m0 + wr * (BM / 2) + fm * 16 + g * 4 + r;
        const int n = n0 + wc * (BN / 2) + fn * 16 + li;
        float c = acc[fm][fn][r];
        if (BIAS) c += bias[n];
        if (RELU) c = fmaxf(c, 0.0f);
        if (OUT == 0) {
          Cf[(size_t)m * Nd + n] = c;
        } else if (OUT == 1) {
          Ch[swz_idx(m, n)] = f2fh(c);
        } else if (OUT == 2) {
          const int mat = n >> 9, h = (n >> 6) & 7, dk = n & 63;
          const int b_ = m >> 10, s_ = m & (kS - 1);
          Ch[((size_t)mat * kM) * kD +
             (((size_t)(b_ * kH + h) * kS + s_) * kDK + dk)] = f2fh(c);
        } else {
          u16 q = f2bh(__expf(c));
          Ch[(size_t)m * Nd + n] = q;
          acc[fm][fn][r] = bh2f(q);
        }
      }
  if (OUT == 3) {
#pragma unroll
    for (int fm = 0; fm < MF; ++fm)
#pragma unroll
      for (int r = 0; r < 4; ++r) {
        float sv = 0.f;
#pragma unroll
        for (int fn = 0; fn < NF; ++fn) sv += acc[fm][fn][r];
        sv += __shfl_xor(sv, 1); sv += __shfl_xor(sv, 2);
        sv += __shfl_xor(sv, 4); sv += __shfl_xor(sv, 8);
        if (li == 0) plds[wc * BM + wr * (BM / 2) + fm * 16 + g * 4 + r] = sv;
      }
    __syncthreads();
    if (t < BM)
      partials[(size_t)(m0 + t) * gridDim.y + blockIdx.y] = plds[t] + plds[BM + t];
  }
}

// ---- MFMA flash attention (fp16, dbuf K/V, online max, DEFERRED sum reduce)
// m_ comes from a cross-lane max-reduce, so all 16 li lanes of a row share
// identical m_/corr -> per-lane partial sums l_ rescaled by corr stay
// consistent; one cross-lane sum reduce AFTER the kt loop suffices.
__global__ __launch_bounds__(256)
void attn_kernel(const u16* __restrict__ qg, const u16* __restrict__ kg,
                 const u16* __restrict__ vg, u16* __restrict__ aoh) {
  __shared__ __align__(16) u16 Kt[2][2][64][40];
  __shared__ __align__(16) u16 Vt[2][2][64][40];
  __shared__ __align__(16) u16 Pt[2][64][40];
  const int t = threadIdx.x;
  const int lane = t & 63;
  const int g = lane >> 4, li = lane & 15;
  const int w = t >> 6;
  const int bh = blockIdx.y;
  const int q0 = blockIdx.x * 64;
  const size_t base = (size_t)bh * kS * kDK;
  const int r = t >> 2, dq = (t & 3) * 16;

  // stage Q via Pt scratch, pull per-wave A-frags
  {
    const u16* src = &qg[base + (size_t)(q0 + r) * kDK + dq];
    u16x8 a = *(const u16x8*)src;
    u16x8 b = *(const u16x8*)(src + 8);
    *(u16x8*)&Pt[dq >> 5][r][dq & 31] = a;
    *(u16x8*)&Pt[dq >> 5][r][(dq & 31) + 8] = b;
  }
  __syncthreads();
  f16x8 qf0 = *(const f16x8*)&Pt[0][w * 16 + li][g * 8];
  f16x8 qf1 = *(const f16x8*)&Pt[1][w * 16 + li][g * 8];
  __syncthreads();   // Pt free for P tiles

  float m_[4] = {-1e30f, -1e30f, -1e30f, -1e30f};
  float l_[4] = {0.f, 0.f, 0.f, 0.f};   // per-lane partials (lane-uniform m_)
  f32x4 apv[4];
#pragma unroll
  for (int i = 0; i < 4; ++i) apv[i] = (f32x4){0.f, 0.f, 0.f, 0.f};

  u16x8 ka, kb, va, vb;
  auto load_tile = [&](int kt) {
    const u16* ks = &kg[base + (size_t)(kt * 64 + r) * kDK + dq];
    ka = *(const u16x8*)ks;
    kb = *(const u16x8*)(ks + 8);
    const u16* vs = &vg[base + (size_t)(kt * 64 + r) * kDK + dq];
    va = *(const u16x8*)vs;
    vb = *(const u16x8*)(vs + 8);
  };
  auto store_tile = [&](int c) {
    *(u16x8*)&Kt[c][dq >> 5][r][dq & 31] = ka;
    *(u16x8*)&Kt[c][dq >> 5][r][(dq & 31) + 8] = kb;
    const int vc = r >> 5, ko = (r & 31) >> 3, kp = r & 7;
#pragma unroll
    for (int i = 0; i < 8; ++i) {
      const int d = dq + i;
      Vt[c][vc][d][((ko ^ (d >> 4)) << 3) | kp] = va[i];
    }
#pragma unroll
    for (int i = 0; i < 8; ++i) {
      const int d = dq + 8 + i;
      Vt[c][vc][d][((ko ^ (d >> 4)) << 3) | kp] = vb[i];
    }
  };

  load_tile(0);
  store_tile(0);
  for (int kt = 0; kt < kS / 64; ++kt) {
    const int c = kt & 1;
    if (kt < kS / 64 - 1) load_tile(kt + 1);   // issue next-tile loads early
    __syncthreads();                            // buf c ready
    f32x4 s[4];
#pragma unroll
    for (int nf = 0; nf < 4; ++nf) {
      f16x8 k0 = *(const f16x8*)&Kt[c][0][nf * 16 + li][g * 8];
      f16x8 k1 = *(const f16x8*)&Kt[c][1][nf * 16 + li][g * 8];
      f32x4 sa = (f32x4){0.f, 0.f, 0.f, 0.f};
      sa = __builtin_amdgcn_mfma_f32_16x16x32_f16(qf0, k0, sa, 0, 0, 0);
      sa = __builtin_amdgcn_mfma_f32_16x16x32_f16(qf1, k1, sa, 0, 0, 0);
      s[nf] = sa;
    }
    float corr[4];
#pragma unroll
    for (int rr = 0; rr < 4; ++rr) {
      float tm = fmaxf(fmaxf(s[0][rr], s[1][rr]), fmaxf(s[2][rr], s[3][rr])) * 0.125f;
      tm = fmaxf(tm, __shfl_xor(tm, 1));
      tm = fmaxf(tm, __shfl_xor(tm, 2));
      tm = fmaxf(tm, __shfl_xor(tm, 4));
      tm = fmaxf(tm, __shfl_xor(tm, 8));
      const float nm = fmaxf(m_[rr], tm);
      corr[rr] = __expf(m_[rr] - nm);
      m_[rr] = nm;
    }
    u16 pb[4][4];
#pragma unroll
    for (int rr = 0; rr < 4; ++rr) {
      float psum = 0.f;
#pragma unroll
      for (int nf = 0; nf < 4; ++nf) {
        float p = __expf(s[nf][rr] * 0.125f - m_[rr]);
        psum += p;
        pb[nf][rr] = f2fh(p);
      }
      l_[rr] = l_[rr] * corr[rr] + psum;   // per-lane partial, no shuffle
#pragma unroll
      for (int nf = 0; nf < 4; ++nf) apv[nf][rr] *= corr[rr];
    }
#pragma unroll
    for (int nf = 0; nf < 4; ++nf)
#pragma unroll
      for (int rr = 0; rr < 4; ++rr)
        Pt[nf >> 1][w * 16 + g * 4 + rr][(nf & 1) * 16 + li] = pb[nf][rr];
    f16x8 p0 = *(const f16x8*)&Pt[0][w * 16 + li][g * 8];
    f16x8 p1 = *(const f16x8*)&Pt[1][w * 16 + li][g * 8];
#pragma unroll
    for (int nf = 0; nf < 4; ++nf) {
      f16x8 v0 = *(const f16x8*)&Vt[c][0][nf * 16 + li][((g ^ nf) & 3) * 8];
      f16x8 v1 = *(const f16x8*)&Vt[c][1][nf * 16 + li][((g ^ nf) & 3) * 8];
      apv[nf] = __builtin_amdgcn_mfma_f32_16x16x32_f16(p0, v0, apv[nf], 0, 0, 0);
      apv[nf] = __builtin_amdgcn_mfma_f32_16x16x32_f16(p1, v1, apv[nf], 0, 0, 0);
    }
    if (kt < kS / 64 - 1) store_tile(c ^ 1);    // write next tile after compute
  }
  // single deferred cross-lane rowsum reduce (over the 16 li lanes)
#pragma unroll
  for (int rr = 0; rr < 4; ++rr) {
    float ts = l_[rr];
    ts += __shfl_xor(ts, 1); ts += __shfl_xor(ts, 2);
    ts += __shfl_xor(ts, 4); ts += __shfl_xor(ts, 8);
    l_[rr] = ts;
  }
  const int b_ = bh >> 3, h_ = bh & 7;
#pragma unroll
  for (int rr = 0; rr < 4; ++rr) {
    const float inv = 1.0f / l_[rr];
    const int row = q0 + w * 16 + g * 4 + rr;
    const int m = b_ * kS + row;
#pragma unroll
    for (int nf = 0; nf < 4; ++nf) {
      const int d = h_ * kDK + nf * 16 + li;
      aoh[swz_idx(m, d)] = f2fh(apv[nf][rr] * inv);
    }
  }
}

// --------------------------------------------- residual + LayerNorm in place
__global__ __launch_bounds__(256)
void ln_kernel(float* __restrict__ x, const float* __restrict__ h,
               const unsigned* __restrict__ gb, u16* __restrict__ xh) {
  const int row = blockIdx.x;
  const int s = row & (kS - 1);
  const int t = threadIdx.x;
  float* xr = x + (size_t)row * kD;
  const float* hr = h + (size_t)row * kD;
  const float v0 = xr[t] + hr[t];
  const float v1 = xr[t + 256] + hr[t + 256];
  float sum = v0 + v1;
  float sq = v0 * v0 + v1 * v1;
#pragma unroll
  for (int off = 1; off < 64; off <<= 1) {
    sum += __shfl_xor(sum, off);
    sq += __shfl_xor(sq, off);
  }
  __shared__ float rs[4], rq[4];
  if ((t & 63) == 0) { rs[t >> 6] = sum; rq[t >> 6] = sq; }
  __syncthreads();
  sum = rs[0] + rs[1] + rs[2] + rs[3];
  sq = rq[0] + rq[1] + rq[2] + rq[3];
  const float mean = sum * (1.0f / kD);
  const float var = fmaxf(sq * (1.0f / kD) - mean * mean, 0.0f);
  const float inv = 1.0f / (sqrtf(var) + 1e-6f);
  const unsigned* gbr = gb + (size_t)s * kD;
  const unsigned p0 = gbr[t], p1 = gbr[t + 256];
  const float o0 = fh2f((u16)p0) * inv * (v0 - mean) + fh2f((u16)(p0 >> 16));
  const float o1 = fh2f((u16)p1) * inv * (v1 - mean) + fh2f((u16)(p1 >> 16));
  xr[t] = o0;
  xr[t + 256] = o1;
  xh[swz_idx(row, t)] = f2fh(o0);
  xh[swz_idx(row, t + 256)] = f2fh(o1);
}

// ---------------- fused rowsum + scale: p = bf16exp / sum, write fp32 d_out
__global__ __launch_bounds__(256)
void scale_kernel(const u16* __restrict__ expb, const float* __restrict__ partials,
                  float* __restrict__ out) {
  const int row = blockIdx.x;
  const int t = threadIdx.x;
  float s = (t < kNB) ? partials[(size_t)row * kNB + t] : 0.f;
#pragma unroll
  for (int off = 1; off < 64; off <<= 1) s += __shfl_xor(s, off);
  __shared__ float red[4];
  if ((t & 63) == 0) red[t >> 6] = s;
  __syncthreads();
  const float inv = 1.0f / (red[0] + red[1] + red[2] + red[3]);
  const u16x8* src = (const u16x8*)(expb + (size_t)row * kV);
  float4* dst = (float4*)(out + (size_t)row * kV);
  for (int i = t; i < kV / 8; i += 256) {
    u16x8 v = src[i];
    float4 a = make_float4(bh2f(v[0]) * inv, bh2f(v[1]) * inv,
                           bh2f(v[2]) * inv, bh2f(v[3]) * inv);
    float4 b = make_float4(bh2f(v[4]) * inv, bh2f(v[5]) * inv,
                           bh2f(v[6]) * inv, bh2f(v[7]) * inv);
    dst[i * 2] = a;
    dst[i * 2 + 1] = b;
  }
}

// ---------------------------------------------------------------------------
extern "C" void kernel_launch(void* const* d_in, const int* in_sizes, int n_in,
                              void* d_out, int out_size, void* d_ws, size_t ws_size,
                              hipStream_t stream) {
  (void)in_sizes; (void)n_in; (void)out_size; (void)ws_size;
  const int* tokens = (const int*)d_in[0];
  const float* emb = (const float*)d_in[1];
  const float* Wq = (const float*)d_in[2];
  const float* Wk = (const float*)d_in[3];
  const float* Wv = (const float*)d_in[4];
  const float* Wo = (const float*)d_in[5];
  const float* lng = (const float*)d_in[6];
  const float* lnb = (const float*)d_in[7];
  const float* w1 = (const float*)d_in[8];
  const float* b1 = (const float*)d_in[9];
  const float* w2 = (const float*)d_in[10];
  const float* b2 = (const float*)d_in[11];

  size_t off = 0;
  auto alloc = [&](size_t bytes) {
    void* p = (char*)d_ws + off;
    off += (bytes + 255) & ~(size_t)255;
    return p;
  };
  const size_t NA = (size_t)kM * kD;
  float* x = (float*)alloc(NA * 4);
  u16* xh = (u16*)alloc(NA * 2);
  u16* qkvb = (u16*)alloc(3 * NA * 2);
  u16* aoh = (u16*)alloc(NA * 2);
  float* t1 = (float*)alloc(NA * 4);
  u16* t1h = (u16*)alloc(NA * 2);
  float* ao2 = (float*)alloc(NA * 4);
  float* partials = (float*)alloc((size_t)kM * kNB * 4);
  u16* expb = (u16*)alloc((size_t)kM * kV * 2);     // 131 MB bf16 exp-logits
  u16* wqkvh = (u16*)alloc((size_t)8 * 1536 * kD * 2);
  u16* woh = (u16*)alloc((size_t)8 * kD * kD * 2);
  u16* w1h = (u16*)alloc((size_t)4 * kD * kD * 2);
  u16* w2h = (u16*)alloc((size_t)4 * kD * kD * 2);
  u16* embh = (u16*)alloc((size_t)kV * kD * 2);
  unsigned* gb = (unsigned*)alloc((size_t)kL * 3 * kS * kD * 4);

  conv_qkv<<<dim3(8, 8, 24), 256, 0, stream>>>(Wq, Wk, Wv, wqkvh);
  conv_sq<<<dim3(8, 8, 16), 256, 0, stream>>>(Wo, w1, w2, woh, w1h, w2h);
  conv_emb<<<kV * kD / 8 / 256, 256, 0, stream>>>(emb, embh);
  conv_gb<<<kL * 3 * kS * kD / 8 / 256, 256, 0, stream>>>(lng, lnb, gb);
  embed_kernel<<<kM, 256, 0, stream>>>(tokens, emb, x, xh);

  for (int l = 0; l < kL; ++l) {
    for (int j = 0; j < 2; ++j) {
      const size_t lj = (size_t)(l * 2 + j);
      mgemm2<128, 128, 2, 0, 0><<<dim3(kM / 128, 12), 256, 0, stream>>>(
          xh, wqkvh + lj * 1536 * kD, nullptr, qkvb, nullptr, nullptr, kD, 1536);
      attn_kernel<<<dim3(kS / 64, kB * kH), 256, 0, stream>>>(
          qkvb, qkvb + NA, qkvb + 2 * NA, aoh);
      mgemm2<64, 64, 0, 0, 0><<<dim3(kM / 64, kD / 64), 256, 0, stream>>>(
          aoh, woh + lj * kD * kD, t1, nullptr, nullptr, nullptr, kD, kD);
      ln_kernel<<<kM, 256, 0, stream>>>(x, t1, gb + (size_t)(l * 3 + j) * kS * kD, xh);
    }
    mgemm2<64, 64, 1, 1, 1><<<dim3(kM / 64, kD / 64), 256, 0, stream>>>(
        xh, w1h + (size_t)l * kD * kD, nullptr, t1h, b1 + (size_t)l * kD,
        nullptr, kD, kD);
    mgemm2<64, 64, 0, 1, 0><<<dim3(kM / 64, kD / 64), 256, 0, stream>>>(
        t1h, w2h + (size_t)l * kD * kD, ao2, nullptr, b2 + (size_t)l * kD,
        nullptr, kD, kD);
    ln_kernel<<<kM, 256, 0, stream>>>(x, ao2, gb + (size_t)(l * 3 + 2) * kS * kD, xh);
  }
  // vocab: bf16 exp(x @ emb^T) -> expb + partials; then fused rowsum+scale
  mgemm2<128, 128, 3, 0, 0><<<dim3(kM / 128, kNB), 256, 0, stream>>>(
      xh, embh, nullptr, expb, nullptr, partials, kD, kV);
  scale_kernel<<<kM, 256, 0, stream>>>(expb, partials, (float*)d_out);
}

// Round 14
// 670.016 us; speedup vs baseline: 1.2963x; 1.0140x over previous
//
#include <hip/hip_runtime.h>
#include <hip/hip_bf16.h>

typedef unsigned short u16;
typedef _Float16 f16x8 __attribute__((ext_vector_type(8)));
typedef float f32x4 __attribute__((ext_vector_type(4)));
typedef unsigned short u16x8 __attribute__((ext_vector_type(8)));
typedef unsigned int u32x4 __attribute__((ext_vector_type(4)));

constexpr int kB = 2;
constexpr int kS = 1024;
constexpr int kD = 512;
constexpr int kH = 8;
constexpr int kDK = 64;
constexpr int kL = 4;
constexpr int kV = 32000;
constexpr int kM = kB * kS;   // 2048
constexpr int kNB = kV / 128; // 250

__device__ __forceinline__ u16 f2fh(float x) {           // fp16 RTN
  _Float16 h = (_Float16)x;
  return __builtin_bit_cast(u16, h);
}
__device__ __forceinline__ float fh2f(u16 h) {
  return (float)__builtin_bit_cast(_Float16, h);
}
__device__ __forceinline__ u16 f2bh(float x) {           // bf16 RTN (exp store)
  unsigned u = __builtin_bit_cast(unsigned, x);
  unsigned r = u + 0x7fffu + ((u >> 16) & 1u);
  return (u16)(r >> 16);
}
__device__ __forceinline__ float bh2f(u16 h) {
  return __builtin_bit_cast(float, (unsigned)h << 16);
}
__device__ __forceinline__ void gload16(const u16* g, u16* l) {
  __builtin_amdgcn_global_load_lds(
      (const __attribute__((address_space(1))) unsigned int*)g,
      (__attribute__((address_space(3))) unsigned int*)l, 16, 0, 0);
}
// swizzled u16 index for element (row, k) in a [*][512] fp16 array
__device__ __forceinline__ size_t swz_idx(int row, int k) {
  return (size_t)row * kD + (k & ~63) + ((((k >> 3) & 7) ^ (row & 7)) << 3) + (k & 7);
}

// ------------------------------------------- weight conversion (transpose)
__global__ __launch_bounds__(256)
void conv_qkv(const float* __restrict__ Wq, const float* __restrict__ Wk,
              const float* __restrict__ Wv, u16* __restrict__ oh) {
  __shared__ float ld[64][65];
  const int kc = blockIdx.x, h = blockIdx.y, z = blockIdx.z;
  const int mat = z >> 3, lj = z & 7;
  const float* src = (mat == 0 ? Wq : mat == 1 ? Wk : Wv) +
                     ((size_t)(lj * kH + h)) * kD * kDK + (size_t)kc * 64 * kDK;
  const int t = threadIdx.x;
#pragma unroll
  for (int i = 0; i < 16; ++i) {
    const int idx = i * 256 + t;
    ld[idx >> 6][idx & 63] = src[idx];
  }
  __syncthreads();
  const int dkr = t >> 2, jb = t & 3;
  const size_t rowbase = ((size_t)lj * 1536 + mat * kD + h * kDK + dkr) * kD + kc * 64;
#pragma unroll
  for (int q = 0; q < 2; ++q) {
    const int jj = jb + q * 4;
    const int jsw = jj ^ (dkr & 7);
    u16x8 hi;
#pragma unroll
    for (int e = 0; e < 8; ++e) hi[e] = f2fh(ld[jj * 8 + e][dkr]);
    *(u16x8*)&oh[rowbase + jsw * 8] = hi;
  }
}

__global__ __launch_bounds__(256)
void conv_sq(const float* __restrict__ Wo, const float* __restrict__ w1,
             const float* __restrict__ w2, u16* __restrict__ woh,
             u16* __restrict__ w1h, u16* __restrict__ w2h) {
  __shared__ float ld[64][65];
  const int kc = blockIdx.x, nc = blockIdx.y, mid = blockIdx.z;
  const float* src;
  u16* dh;
  if (mid < 8) { src = Wo + (size_t)mid * kD * kD; dh = woh + (size_t)mid * kD * kD; }
  else if (mid < 12) { int l = mid - 8; src = w1 + (size_t)l * kD * kD; dh = w1h + (size_t)l * kD * kD; }
  else { int l = mid - 12; src = w2 + (size_t)l * kD * kD; dh = w2h + (size_t)l * kD * kD; }
  const int t = threadIdx.x;
#pragma unroll
  for (int i = 0; i < 16; ++i) {
    const int idx = i * 256 + t;
    const int kl = idx >> 6, nl = idx & 63;
    ld[kl][nl] = src[(size_t)(kc * 64 + kl) * kD + nc * 64 + nl];
  }
  __syncthreads();
  const int nr = t >> 2, jb = t & 3;
  const size_t rowbase = (size_t)(nc * 64 + nr) * kD + kc * 64;
#pragma unroll
  for (int q = 0; q < 2; ++q) {
    const int jj = jb + q * 4;
    const int jsw = jj ^ (nr & 7);
    u16x8 hi;
#pragma unroll
    for (int e = 0; e < 8; ++e) hi[e] = f2fh(ld[jj * 8 + e][nr]);
    *(u16x8*)&dh[rowbase + jsw * 8] = hi;
  }
}

__global__ __launch_bounds__(256)
void conv_emb(const float* __restrict__ emb, u16* __restrict__ oh) {
  const int chunk = blockIdx.x * 256 + threadIdx.x;
  const int n = chunk >> 6, j = chunk & 63;
  const float* s = &emb[(size_t)n * kD + j * 8];
  float4 a = *(const float4*)s, b = *(const float4*)(s + 4);
  u16x8 hi;
  hi[0] = f2fh(a.x); hi[1] = f2fh(a.y); hi[2] = f2fh(a.z); hi[3] = f2fh(a.w);
  hi[4] = f2fh(b.x); hi[5] = f2fh(b.y); hi[6] = f2fh(b.z); hi[7] = f2fh(b.w);
  *(u16x8*)&oh[(size_t)n * kD + (j & ~7) * 8 + (((j & 7) ^ (n & 7)) << 3)] = hi;
}

// LN gain/bias fp32 -> interleaved fp16 pairs (g,b) packed in one u32 per elem
__global__ __launch_bounds__(256)
void conv_gb(const float* __restrict__ g, const float* __restrict__ b,
             unsigned* __restrict__ out) {
  const size_t e0 = ((size_t)blockIdx.x * 256 + threadIdx.x) * 8;
  float4 ga = *(const float4*)&g[e0], gc = *(const float4*)&g[e0 + 4];
  float4 ba = *(const float4*)&b[e0], bc = *(const float4*)&b[e0 + 4];
  u32x4 o0, o1;
  o0[0] = (unsigned)f2fh(ga.x) | ((unsigned)f2fh(ba.x) << 16);
  o0[1] = (unsigned)f2fh(ga.y) | ((unsigned)f2fh(ba.y) << 16);
  o0[2] = (unsigned)f2fh(ga.z) | ((unsigned)f2fh(ba.z) << 16);
  o0[3] = (unsigned)f2fh(ga.w) | ((unsigned)f2fh(ba.w) << 16);
  o1[0] = (unsigned)f2fh(gc.x) | ((unsigned)f2fh(bc.x) << 16);
  o1[1] = (unsigned)f2fh(gc.y) | ((unsigned)f2fh(bc.y) << 16);
  o1[2] = (unsigned)f2fh(gc.z) | ((unsigned)f2fh(bc.z) << 16);
  o1[3] = (unsigned)f2fh(gc.w) | ((unsigned)f2fh(bc.w) << 16);
  *(u32x4*)&out[e0] = o0;
  *(u32x4*)&out[e0 + 4] = o1;
}

// ---------------------------------------------------------------- embed + PE
__global__ __launch_bounds__(256)
void embed_kernel(const int* __restrict__ tokens, const float* __restrict__ emb,
                  float* __restrict__ x, u16* __restrict__ xh) {
  const int row = blockIdx.x;
  const int s = row & (kS - 1);
  const int tok = tokens[row];
  const float scl = sqrtf((float)kD);
  for (int d = threadIdx.x; d < kD; d += 256) {
    float e = emb[(size_t)tok * kD + d];
    float den = powf(10000.0f, 2.0f * (float)d / (float)kD);
    float ang = (float)s / den;
    float pe = ((d & 1) == 0) ? sinf(ang) : cosf(ang);
    float o = (e + pe) * scl;
    x[(size_t)row * kD + d] = o;
    xh[swz_idx(row, d)] = f2fh(o);
  }
}

// --------------------------------------------------- MFMA GEMM, fp16 inputs
// C = A @ B^T. A: [M][K] fp16 pre-swizzled. B: [N][K] fp16 pre-swizzled.
// 2-phase double-buffered K-loop with global_load_lds(16B) staging.
// Supports BM != BN (BM,BN multiples of 32; 256 threads, 2x2 wave grid).
// OUT: 0 fp32 [M][Nd]; 1 fp16 swizzled [M][512]; 2 qkv fp16 scatter [b,h,s,dk];
//      3 bf16 exp(c) [M][Nd] + deterministic per-row partial sums.
template <int BM, int BN, int OUT, int BIAS, int RELU>
__global__ __launch_bounds__(256)
void mgemm2(const u16* __restrict__ Ah, const u16* __restrict__ Bh,
            float* __restrict__ Cf, u16* __restrict__ Ch,
            const float* __restrict__ bias, float* __restrict__ partials,
            int Kd, int Nd) {
  constexpr int MF = BM / 32, NF = BN / 32;
  constexpr int TA = BM * 64;                       // u16 per A tile
  constexpr int TB = BN * 64;                       // u16 per B tile
  constexpr int BUF = TA + TB;
  __shared__ __align__(16) u16 lds[2 * BUF];
  __shared__ float plds[OUT == 3 ? 2 * BM : 1];
  const int t = threadIdx.x;
  const int lane = t & 63, g = lane >> 4, li = lane & 15;
  const int w = t >> 6, wr = w >> 1, wc = w & 1;
  const int m0 = blockIdx.x * BM, n0 = blockIdx.y * BN;

  f32x4 acc[MF][NF];
#pragma unroll
  for (int i = 0; i < MF; ++i)
#pragma unroll
    for (int j = 0; j < NF; ++j) acc[i][j] = (f32x4){0.f, 0.f, 0.f, 0.f};

  auto stage = [&](int c, int k0) {
    u16* base = &lds[c * BUF];
#pragma unroll
    for (int it = 0; it < (BM * 8) / 256; ++it) {
      const int idx = it * 256 + t;
      gload16(&Ah[(size_t)(m0 + (idx >> 3)) * Kd + k0 + (idx & 7) * 8],
              &base[idx * 8]);
    }
#pragma unroll
    for (int it = 0; it < (BN * 8) / 256; ++it) {
      const int idx = it * 256 + t;
      gload16(&Bh[(size_t)(n0 + (idx >> 3)) * Kd + k0 + (idx & 7) * 8],
              &base[TA + idx * 8]);
    }
  };
  auto compute = [&](int c) {
    const u16* base = &lds[c * BUF];
#pragma unroll
    for (int s = 0; s < 2; ++s) {
      const int s4g = s * 4 + g;
      f16x8 fah[MF], fbh[NF];
#pragma unroll
      for (int fm = 0; fm < MF; ++fm) {
        const int row = wr * (BM / 2) + fm * 16 + li;
        fah[fm] = *(const f16x8*)&base[row * 64 + ((s4g ^ (row & 7)) << 3)];
      }
#pragma unroll
      for (int fn = 0; fn < NF; ++fn) {
        const int row = wc * (BN / 2) + fn * 16 + li;
        fbh[fn] = *(const f16x8*)&base[TA + row * 64 + ((s4g ^ (row & 7)) << 3)];
      }
#pragma unroll
      for (int fm = 0; fm < MF; ++fm)
#pragma unroll
        for (int fn = 0; fn < NF; ++fn)
          acc[fm][fn] = __builtin_amdgcn_mfma_f32_16x16x32_f16(
              fah[fm], fbh[fn], acc[fm][fn], 0, 0, 0);
    }
  };

  stage(0, 0);
  __syncthreads();
  int cur = 0;
  for (int k0 = 64; k0 < Kd; k0 += 64) {
    stage(cur ^ 1, k0);
    compute(cur);
    __syncthreads();
    cur ^= 1;
  }
  compute(cur);

  // epilogue: D col = lane&15, row = (lane>>4)*4 + reg
#pragma unroll
  for (int fm = 0; fm < MF; ++fm)
#pragma unroll
    for (int fn = 0; fn < NF; ++fn)
#pragma unroll
      for (int r = 0; r < 4; ++r) {
        const int m = m0 + wr * (BM / 2) + fm * 16 + g * 4 + r;
        const int n = n0 + wc * (BN / 2) + fn * 16 + li;
        float c = acc[fm][fn][r];
        if (BIAS) c += bias[n];
        if (RELU) c = fmaxf(c, 0.0f);
        if (OUT == 0) {
          Cf[(size_t)m * Nd + n] = c;
        } else if (OUT == 1) {
          Ch[swz_idx(m, n)] = f2fh(c);
        } else if (OUT == 2) {
          const int mat = n >> 9, h = (n >> 6) & 7, dk = n & 63;
          const int b_ = m >> 10, s_ = m & (kS - 1);
          Ch[((size_t)mat * kM) * kD +
             (((size_t)(b_ * kH + h) * kS + s_) * kDK + dk)] = f2fh(c);
        } else {
          u16 q = f2bh(__expf(c));
          Ch[(size_t)m * Nd + n] = q;
          acc[fm][fn][r] = bh2f(q);
        }
      }
  if (OUT == 3) {
#pragma unroll
    for (int fm = 0; fm < MF; ++fm)
#pragma unroll
      for (int r = 0; r < 4; ++r) {
        float sv = 0.f;
#pragma unroll
        for (int fn = 0; fn < NF; ++fn) sv += acc[fm][fn][r];
        sv += __shfl_xor(sv, 1); sv += __shfl_xor(sv, 2);
        sv += __shfl_xor(sv, 4); sv += __shfl_xor(sv, 8);
        if (li == 0) plds[wc * BM + wr * (BM / 2) + fm * 16 + g * 4 + r] = sv;
      }
    __syncthreads();
    if (t < BM)
      partials[(size_t)(m0 + t) * gridDim.y + blockIdx.y] = plds[t] + plds[BM + t];
  }
}

// ---- MFMA flash attention (fp16, dbuf K/V, online max, deferred sum reduce)
__global__ __launch_bounds__(256)
void attn_kernel(const u16* __restrict__ qg, const u16* __restrict__ kg,
                 const u16* __restrict__ vg, u16* __restrict__ aoh) {
  __shared__ __align__(16) u16 Kt[2][2][64][40];
  __shared__ __align__(16) u16 Vt[2][2][64][40];
  __shared__ __align__(16) u16 Pt[2][64][40];
  const int t = threadIdx.x;
  const int lane = t & 63;
  const int g = lane >> 4, li = lane & 15;
  const int w = t >> 6;
  const int bh = blockIdx.y;
  const int q0 = blockIdx.x * 64;
  const size_t base = (size_t)bh * kS * kDK;
  const int r = t >> 2, dq = (t & 3) * 16;

  // stage Q via Pt scratch, pull per-wave A-frags
  {
    const u16* src = &qg[base + (size_t)(q0 + r) * kDK + dq];
    u16x8 a = *(const u16x8*)src;
    u16x8 b = *(const u16x8*)(src + 8);
    *(u16x8*)&Pt[dq >> 5][r][dq & 31] = a;
    *(u16x8*)&Pt[dq >> 5][r][(dq & 31) + 8] = b;
  }
  __syncthreads();
  f16x8 qf0 = *(const f16x8*)&Pt[0][w * 16 + li][g * 8];
  f16x8 qf1 = *(const f16x8*)&Pt[1][w * 16 + li][g * 8];
  __syncthreads();   // Pt free for P tiles

  float m_[4] = {-1e30f, -1e30f, -1e30f, -1e30f};
  float l_[4] = {0.f, 0.f, 0.f, 0.f};   // per-lane partials (lane-uniform m_)
  f32x4 apv[4];
#pragma unroll
  for (int i = 0; i < 4; ++i) apv[i] = (f32x4){0.f, 0.f, 0.f, 0.f};

  u16x8 ka, kb, va, vb;
  auto load_tile = [&](int kt) {
    const u16* ks = &kg[base + (size_t)(kt * 64 + r) * kDK + dq];
    ka = *(const u16x8*)ks;
    kb = *(const u16x8*)(ks + 8);
    const u16* vs = &vg[base + (size_t)(kt * 64 + r) * kDK + dq];
    va = *(const u16x8*)vs;
    vb = *(const u16x8*)(vs + 8);
  };
  auto store_tile = [&](int c) {
    *(u16x8*)&Kt[c][dq >> 5][r][dq & 31] = ka;
    *(u16x8*)&Kt[c][dq >> 5][r][(dq & 31) + 8] = kb;
    const int vc = r >> 5, ko = (r & 31) >> 3, kp = r & 7;
#pragma unroll
    for (int i = 0; i < 8; ++i) {
      const int d = dq + i;
      Vt[c][vc][d][((ko ^ (d >> 4)) << 3) | kp] = va[i];
    }
#pragma unroll
    for (int i = 0; i < 8; ++i) {
      const int d = dq + 8 + i;
      Vt[c][vc][d][((ko ^ (d >> 4)) << 3) | kp] = vb[i];
    }
  };

  load_tile(0);
  store_tile(0);
  for (int kt = 0; kt < kS / 64; ++kt) {
    const int c = kt & 1;
    if (kt < kS / 64 - 1) load_tile(kt + 1);   // issue next-tile loads early
    __syncthreads();                            // buf c ready
    f32x4 s[4];
#pragma unroll
    for (int nf = 0; nf < 4; ++nf) {
      f16x8 k0 = *(const f16x8*)&Kt[c][0][nf * 16 + li][g * 8];
      f16x8 k1 = *(const f16x8*)&Kt[c][1][nf * 16 + li][g * 8];
      f32x4 sa = (f32x4){0.f, 0.f, 0.f, 0.f};
      sa = __builtin_amdgcn_mfma_f32_16x16x32_f16(qf0, k0, sa, 0, 0, 0);
      sa = __builtin_amdgcn_mfma_f32_16x16x32_f16(qf1, k1, sa, 0, 0, 0);
      s[nf] = sa;
    }
    float corr[4];
#pragma unroll
    for (int rr = 0; rr < 4; ++rr) {
      float tm = fmaxf(fmaxf(s[0][rr], s[1][rr]), fmaxf(s[2][rr], s[3][rr])) * 0.125f;
      tm = fmaxf(tm, __shfl_xor(tm, 1));
      tm = fmaxf(tm, __shfl_xor(tm, 2));
      tm = fmaxf(tm, __shfl_xor(tm, 4));
      tm = fmaxf(tm, __shfl_xor(tm, 8));
      const float nm = fmaxf(m_[rr], tm);
      corr[rr] = __expf(m_[rr] - nm);
      m_[rr] = nm;
    }
    u16 pb[4][4];
#pragma unroll
    for (int rr = 0; rr < 4; ++rr) {
      float psum = 0.f;
#pragma unroll
      for (int nf = 0; nf < 4; ++nf) {
        float p = __expf(s[nf][rr] * 0.125f - m_[rr]);
        psum += p;
        pb[nf][rr] = f2fh(p);
      }
      l_[rr] = l_[rr] * corr[rr] + psum;   // per-lane partial, no shuffle
#pragma unroll
      for (int nf = 0; nf < 4; ++nf) apv[nf][rr] *= corr[rr];
    }
#pragma unroll
    for (int nf = 0; nf < 4; ++nf)
#pragma unroll
      for (int rr = 0; rr < 4; ++rr)
        Pt[nf >> 1][w * 16 + g * 4 + rr][(nf & 1) * 16 + li] = pb[nf][rr];
    f16x8 p0 = *(const f16x8*)&Pt[0][w * 16 + li][g * 8];
    f16x8 p1 = *(const f16x8*)&Pt[1][w * 16 + li][g * 8];
#pragma unroll
    for (int nf = 0; nf < 4; ++nf) {
      f16x8 v0 = *(const f16x8*)&Vt[c][0][nf * 16 + li][((g ^ nf) & 3) * 8];
      f16x8 v1 = *(const f16x8*)&Vt[c][1][nf * 16 + li][((g ^ nf) & 3) * 8];
      apv[nf] = __builtin_amdgcn_mfma_f32_16x16x32_f16(p0, v0, apv[nf], 0, 0, 0);
      apv[nf] = __builtin_amdgcn_mfma_f32_16x16x32_f16(p1, v1, apv[nf], 0, 0, 0);
    }
    if (kt < kS / 64 - 1) store_tile(c ^ 1);    // write next tile after compute
  }
  // single deferred cross-lane rowsum reduce (over the 16 li lanes)
#pragma unroll
  for (int rr = 0; rr < 4; ++rr) {
    float ts = l_[rr];
    ts += __shfl_xor(ts, 1); ts += __shfl_xor(ts, 2);
    ts += __shfl_xor(ts, 4); ts += __shfl_xor(ts, 8);
    l_[rr] = ts;
  }
  const int b_ = bh >> 3, h_ = bh & 7;
#pragma unroll
  for (int rr = 0; rr < 4; ++rr) {
    const float inv = 1.0f / l_[rr];
    const int row = q0 + w * 16 + g * 4 + rr;
    const int m = b_ * kS + row;
#pragma unroll
    for (int nf = 0; nf < 4; ++nf) {
      const int d = h_ * kDK + nf * 16 + li;
      aoh[swz_idx(m, d)] = f2fh(apv[nf][rr] * inv);
    }
  }
}

// --------------------------------------------- residual + LayerNorm in place
__global__ __launch_bounds__(256)
void ln_kernel(float* __restrict__ x, const float* __restrict__ h,
               const unsigned* __restrict__ gb, u16* __restrict__ xh) {
  const int row = blockIdx.x;
  const int s = row & (kS - 1);
  const int t = threadIdx.x;
  float* xr = x + (size_t)row * kD;
  const float* hr = h + (size_t)row * kD;
  const float v0 = xr[t] + hr[t];
  const float v1 = xr[t + 256] + hr[t + 256];
  float sum = v0 + v1;
  float sq = v0 * v0 + v1 * v1;
#pragma unroll
  for (int off = 1; off < 64; off <<= 1) {
    sum += __shfl_xor(sum, off);
    sq += __shfl_xor(sq, off);
  }
  __shared__ float rs[4], rq[4];
  if ((t & 63) == 0) { rs[t >> 6] = sum; rq[t >> 6] = sq; }
  __syncthreads();
  sum = rs[0] + rs[1] + rs[2] + rs[3];
  sq = rq[0] + rq[1] + rq[2] + rq[3];
  const float mean = sum * (1.0f / kD);
  const float var = fmaxf(sq * (1.0f / kD) - mean * mean, 0.0f);
  const float inv = 1.0f / (sqrtf(var) + 1e-6f);
  const unsigned* gbr = gb + (size_t)s * kD;
  const unsigned p0 = gbr[t], p1 = gbr[t + 256];
  const float o0 = fh2f((u16)p0) * inv * (v0 - mean) + fh2f((u16)(p0 >> 16));
  const float o1 = fh2f((u16)p1) * inv * (v1 - mean) + fh2f((u16)(p1 >> 16));
  xr[t] = o0;
  xr[t + 256] = o1;
  xh[swz_idx(row, t)] = f2fh(o0);
  xh[swz_idx(row, t + 256)] = f2fh(o1);
}

// ---------------- fused rowsum + scale: p = bf16exp / sum, write fp32 d_out
__global__ __launch_bounds__(256)
void scale_kernel(const u16* __restrict__ expb, const float* __restrict__ partials,
                  float* __restrict__ out) {
  const int row = blockIdx.x;
  const int t = threadIdx.x;
  float s = (t < kNB) ? partials[(size_t)row * kNB + t] : 0.f;
#pragma unroll
  for (int off = 1; off < 64; off <<= 1) s += __shfl_xor(s, off);
  __shared__ float red[4];
  if ((t & 63) == 0) red[t >> 6] = s;
  __syncthreads();
  const float inv = 1.0f / (red[0] + red[1] + red[2] + red[3]);
  const u16x8* src = (const u16x8*)(expb + (size_t)row * kV);
  float4* dst = (float4*)(out + (size_t)row * kV);
  for (int i = t; i < kV / 8; i += 256) {
    u16x8 v = src[i];
    float4 a = make_float4(bh2f(v[0]) * inv, bh2f(v[1]) * inv,
                           bh2f(v[2]) * inv, bh2f(v[3]) * inv);
    float4 b = make_float4(bh2f(v[4]) * inv, bh2f(v[5]) * inv,
                           bh2f(v[6]) * inv, bh2f(v[7]) * inv);
    dst[i * 2] = a;
    dst[i * 2 + 1] = b;
  }
}

// ---------------------------------------------------------------------------
extern "C" void kernel_launch(void* const* d_in, const int* in_sizes, int n_in,
                              void* d_out, int out_size, void* d_ws, size_t ws_size,
                              hipStream_t stream) {
  (void)in_sizes; (void)n_in; (void)out_size; (void)ws_size;
  const int* tokens = (const int*)d_in[0];
  const float* emb = (const float*)d_in[1];
  const float* Wq = (const float*)d_in[2];
  const float* Wk = (const float*)d_in[3];
  const float* Wv = (const float*)d_in[4];
  const float* Wo = (const float*)d_in[5];
  const float* lng = (const float*)d_in[6];
  const float* lnb = (const float*)d_in[7];
  const float* w1 = (const float*)d_in[8];
  const float* b1 = (const float*)d_in[9];
  const float* w2 = (const float*)d_in[10];
  const float* b2 = (const float*)d_in[11];

  size_t off = 0;
  auto alloc = [&](size_t bytes) {
    void* p = (char*)d_ws + off;
    off += (bytes + 255) & ~(size_t)255;
    return p;
  };
  const size_t NA = (size_t)kM * kD;
  float* x = (float*)alloc(NA * 4);
  u16* xh = (u16*)alloc(NA * 2);
  u16* qkvb = (u16*)alloc(3 * NA * 2);
  u16* aoh = (u16*)alloc(NA * 2);
  float* t1 = (float*)alloc(NA * 4);
  u16* t1h = (u16*)alloc(NA * 2);
  float* ao2 = (float*)alloc(NA * 4);
  float* partials = (float*)alloc((size_t)kM * kNB * 4);
  u16* expb = (u16*)alloc((size_t)kM * kV * 2);     // 131 MB bf16 exp-logits
  u16* wqkvh = (u16*)alloc((size_t)8 * 1536 * kD * 2);
  u16* woh = (u16*)alloc((size_t)8 * kD * kD * 2);
  u16* w1h = (u16*)alloc((size_t)4 * kD * kD * 2);
  u16* w2h = (u16*)alloc((size_t)4 * kD * kD * 2);
  u16* embh = (u16*)alloc((size_t)kV * kD * 2);
  unsigned* gb = (unsigned*)alloc((size_t)kL * 3 * kS * kD * 4);

  conv_qkv<<<dim3(8, 8, 24), 256, 0, stream>>>(Wq, Wk, Wv, wqkvh);
  conv_sq<<<dim3(8, 8, 16), 256, 0, stream>>>(Wo, w1, w2, woh, w1h, w2h);
  conv_emb<<<kV * kD / 8 / 256, 256, 0, stream>>>(emb, embh);
  conv_gb<<<kL * 3 * kS * kD / 8 / 256, 256, 0, stream>>>(lng, lnb, gb);
  embed_kernel<<<kM, 256, 0, stream>>>(tokens, emb, x, xh);

  for (int l = 0; l < kL; ++l) {
    for (int j = 0; j < 2; ++j) {
      const size_t lj = (size_t)(l * 2 + j);
      mgemm2<64, 128, 2, 0, 0><<<dim3(kM / 64, 12), 256, 0, stream>>>(
          xh, wqkvh + lj * 1536 * kD, nullptr, qkvb, nullptr, nullptr, kD, 1536);
      attn_kernel<<<dim3(kS / 64, kB * kH), 256, 0, stream>>>(
          qkvb, qkvb + NA, qkvb + 2 * NA, aoh);
      mgemm2<32, 64, 0, 0, 0><<<dim3(kM / 32, kD / 64), 256, 0, stream>>>(
          aoh, woh + lj * kD * kD, t1, nullptr, nullptr, nullptr, kD, kD);
      ln_kernel<<<kM, 256, 0, stream>>>(x, t1, gb + (size_t)(l * 3 + j) * kS * kD, xh);
    }
    mgemm2<32, 64, 1, 1, 1><<<dim3(kM / 32, kD / 64), 256, 0, stream>>>(
        xh, w1h + (size_t)l * kD * kD, nullptr, t1h, b1 + (size_t)l * kD,
        nullptr, kD, kD);
    mgemm2<32, 64, 0, 1, 0><<<dim3(kM / 32, kD / 64), 256, 0, stream>>>(
        t1h, w2h + (size_t)l * kD * kD, ao2, nullptr, b2 + (size_t)l * kD,
        nullptr, kD, kD);
    ln_kernel<<<kM, 256, 0, stream>>>(x, ao2, gb + (size_t)(l * 3 + 2) * kS * kD, xh);
  }
  // vocab: bf16 exp(x @ emb^T) -> expb + partials; then fused rowsum+scale
  mgemm2<128, 128, 3, 0, 0><<<dim3(kM / 128, kNB), 256, 0, stream>>>(
      xh, embh, nullptr, expb, nullptr, partials, kD, kV);
  scale_kernel<<<kM, 256, 0, stream>>>(expb, partials, (float*)d_out);
}